// Round 16
// baseline (431.921 us; speedup 1.0000x reference)
//
#include <hip/hip_runtime.h>

typedef _Float16 f16;
typedef f16 f16x8 __attribute__((ext_vector_type(8)));
typedef float f32x4 __attribute__((ext_vector_type(4)));

#define NB 16384
#define D 400
#define DP 416
#define NEXP 8
#define NTASK 10
#define NKT 13

#define MEMFENCE asm volatile("" ::: "memory")
#define BAR() do{ MEMFENCE; __builtin_amdgcn_s_barrier(); MEMFENCE; }while(0)
#define VM(N) asm volatile("s_waitcnt vmcnt(" #N ")" ::: "memory")
#define LGKM0 asm volatile("s_waitcnt lgkmcnt(0)" ::: "memory")

static __device__ __forceinline__ f32x4 mfma16x32(f16x8 a, f16x8 b, f32x4 c){
  return __builtin_amdgcn_mfma_f32_16x16x32_f16(a, b, c, 0, 0, 0);
}
static __device__ __forceinline__ void g2l(const void* g, void* l){
  __builtin_amdgcn_global_load_lds((const __attribute__((address_space(1))) void*)g,
      (__attribute__((address_space(3))) void*)l, 16, 0, 0);
}
static __device__ __forceinline__ f16x8 scale8(f16x8 a, f16 s){
  f16x8 r;
  #pragma unroll
  for (int e=0;e<8;e++) r[e] = a[e]*s;
  return r;
}

// ---- duo staging (verified R4/R6/R9/R10): 2 adjacent 16-col tiles for one kt,
// [16 rows][128B], chunk ^= row&7; LDS dest linear, global source pre-swizzled.
static __device__ __forceinline__ void stage_duo(const char* wbase, char* lds, int kt,
                                                 int t0, int dd, int h, int lane){
  const int r = lane >> 3, c = lane & 7, cg = c ^ r;
  g2l(wbase + (size_t)((t0 + dd*2 + (cg>>2))*16 + h*8 + r)*832 + (size_t)kt*64 + (cg&3)*16,
      lds + dd*2048 + h*1024);
}
static __device__ __forceinline__ f16x8 rdB(const f16* buf, int dloc, int t, int lhi, int l15){
  return *(const f16x8*)(buf + dloc*1024 + l15*64 + ((((t*4+lhi) ^ (l15&7)))<<3));
}
// lact: [rows][416] f16, 16B-chunk XOR swizzle on chunks<48
static __device__ __forceinline__ f16x8 rdL(const f16* lact, int r, int kt, int lhi){
  int q = kt*4 + lhi;
  int c = (q < 48) ? (q ^ (r&7)) : q;
  return *(const f16x8*)(lact + r*416 + (c<<3));
}
static __device__ __forceinline__ int lact_idx(int r, int col){
  int q = col >> 3;
  int c = (q < 48) ? (q ^ (r&7)) : q;
  return r*416 + (c<<3) + (col&7);
}
// full-width 416-col staging for one kt over 4 waves / 8 waves
static __device__ __forceinline__ void stageB4(const char* wb, char* buf, int kt,
                                               int wv, int lane){
  for (int u = wv; u < 26; u += 4) stage_duo(wb, buf, kt, 0, u>>1, u&1, lane);
}
static __device__ __forceinline__ void stageB8(const char* wb, char* buf, int kt,
                                               int wv, int lane){
  for (int u = wv; u < 26; u += 8) stage_duo(wb, buf, kt, 0, u>>1, u&1, lane);
}

// ---------------- prep kernels ----------------

__global__ void k_build_x(const float* __restrict__ obs, const float* __restrict__ act,
                          f16* __restrict__ x)
{
  int idx = blockIdx.x*256 + threadIdx.x;
  int b = idx >> 6, c = idx & 63;
  float v = 0.f;
  if (c < 39) v = obs[b*39 + c];
  else if (c < 43) v = act[b*4 + (c - 39)];
  x[idx] = (f16)v;
}

__global__ void k_transpose_all(
    const float* __restrict__ bb_w1, const float* __restrict__ bb_w2,
    const float* __restrict__ ex_w1, const float* __restrict__ ex_w2,
    const float* __restrict__ tw_w1, const float* __restrict__ tw_w2,
    f16* __restrict__ bbw1T, f16* __restrict__ bbw2T,
    f16* __restrict__ exw1T, f16* __restrict__ exw2T,
    f16* __restrict__ tw1T,  f16* __restrict__ tw2T)
{
  __shared__ float t[32][33];
  const int z = blockIdx.z;
  const float* in; f16* out; int K = D;
  if (z == 0){ in = bb_w1; out = bbw1T; K = 43; }
  else if (z == 1){ in = bb_w2; out = bbw2T; }
  else if (z < 10){ in = ex_w1 + (size_t)(z-2)*D*D;  out = exw1T + (size_t)(z-2)*DP*DP; }
  else if (z < 18){ in = ex_w2 + (size_t)(z-10)*D*D; out = exw2T + (size_t)(z-10)*DP*DP; }
  else if (z == 18){ in = tw_w1; out = tw1T; }
  else { in = tw_w2; out = tw2T; }
  int tx = threadIdx.x & 31, ty = threadIdx.x >> 5;
  int n0 = blockIdx.x*32, k0 = blockIdx.y*32;
  #pragma unroll
  for (int r=0;r<4;r++){
    int k = k0 + ty + r*8, nn = n0 + tx;
    t[ty + r*8][tx] = (k < K && nn < D) ? in[(size_t)k*D + nn] : 0.f;
  }
  __syncthreads();
  #pragma unroll
  for (int r=0;r<4;r++){
    int nn = n0 + ty + r*8, kp = k0 + tx;
    if (nn < DP && kp < DP) out[(size_t)nn*DP + kp] = (f16)t[tx][ty + r*8];
  }
}

__global__ void k_val_pad(const float* __restrict__ in, f16* __restrict__ out)
{
  int idx = blockIdx.x*256 + threadIdx.x;
  if (idx >= NEXP*DP*DP) return;
  int c = idx % DP, r = (idx / DP) % DP, n = idx / (DP*DP);
  float v = (r < D && c < D) ? in[((size_t)n*D + r)*D + c] : 0.f;
  out[idx] = (f16)v;
}

__global__ void k_kq(const float* __restrict__ key_mat, const float* __restrict__ tq,
                     float* __restrict__ kq)
{
  __shared__ float kcol[D*32];
  __shared__ float tqs[NTASK*D];
  const int n = blockIdx.x, cb = blockIdx.y, tid = threadIdx.x;
  const int c0 = cb*32;
  const float* km = key_mat + (size_t)n*D*D;
  for (int idx=tid; idx<NTASK*D; idx+=256) tqs[idx] = tq[idx];
  for (int idx=tid; idx<D*32; idx+=256){
    int i = idx>>5, c = idx&31;
    int col = c0 + c;
    kcol[idx] = (col < D) ? km[(size_t)i*D + col] : 0.f;
  }
  __syncthreads();
  const int c = tid & 31, tg = tid >> 5;
  #pragma unroll
  for (int rep=0; rep<2; rep++){
    int t = tg + rep*8;
    if (t < NTASK){
      float acc = 0.f;
      for (int i=0;i<D;i++) acc += kcol[i*32+c] * tqs[t*D+i];
      int col = c0 + c;
      if (col < DP) kq[((size_t)n*NTASK + t)*DP + col] = acc;
    }
  }
}

// ---------------- compute kernels ----------------

#define MFMA13(a0_, BUF) do {                                                   \
    __builtin_amdgcn_s_setprio(1);                                              \
    _Pragma("unroll")                                                           \
    for (int j=0;j<13;j++){                                                     \
      int tj = ch*13 + j;                                                       \
      f16x8 b = rdB((BUF), tj>>1, tj&1, lhi, l15);                              \
      acc[j] = mfma16x32((a0_), b, acc[j]);                                     \
    }                                                                           \
    __builtin_amdgcn_s_setprio(0);                                              \
  } while(0)

// BK=64 staging over 4 waves: kh-major 26+26 units; half phase = 26 (kh0 only).
#define STAGE_W(wb_, buf_, p_, full_) do{                                       \
    int tot_ = (full_) ? 52 : 26;                                               \
    for (int u = wv; u < tot_; u += 4){                                         \
      int kh_ = (u >= 26) ? 1 : 0, uu_ = u - (kh_ ? 26 : 0);                    \
      stage_duo((wb_), (char*)(buf_)[kh_], 2*(p_)+kh_, 0, uu_>>1, uu_&1, lane); \
    }                                                                           \
  } while(0)

// experts: SAME footprint/traffic/sync as R15 (BM=64, lact, 2 blocks/CU, VM(0)
// 2-barrier, K-rotation) but 512 thr = 8 waves of 16 rows -> 16 waves/CU.
__global__ __launch_bounds__(512,2) void k_experts(
    const f16* __restrict__ h16, const f16* __restrict__ w1T, const float* __restrict__ b1s,
    const f16* __restrict__ w2T, const float* __restrict__ b2s,
    f16* __restrict__ e16, const float* __restrict__ kqg, const int* __restrict__ task,
    float* __restrict__ scores)
{
  __shared__ f16 bufB[13*1024];
  __shared__ f16 lact[64*416];
  float (*psum)[2] = (float(*)[2])lact;
  const int tid = threadIdx.x, lane = tid & 63, wv = tid >> 6;   // wv 0..7
  const int l15 = lane & 15, lhi = lane >> 4;
  const int rh = wv >> 1, ch = wv & 1;                           // rh 0..3 (16 rows)
  const int n = blockIdx.x;
  const int rowbase = blockIdx.y * 64;
  const int K0 = ((blockIdx.x + blockIdx.y) & 1) * 7;
  const f32x4 Z4 = {0,0,0,0};
  f32x4 acc[13];

  const char* wb1 = (const char*)(w1T + (size_t)n*DP*DP);
  const char* wb2 = (const char*)(w2T + (size_t)n*DP*DP);
  const f16* Ab = h16 + (size_t)(rowbase + rh*16 + l15)*DP;

  // GEMM1 (kt order rotated)
  #pragma unroll
  for (int j=0;j<13;j++) acc[j]=Z4;
  f16x8 a0 = *(const f16x8*)(Ab + K0*32 + lhi*8);
  stageB8(wb1, (char*)bufB, K0, wv, lane);
  for (int kt=0; kt<NKT; kt++){
    VM(0); BAR();
    MFMA13(a0, bufB);
    BAR();
    if (kt < NKT-1){
      int kn = kt + 1 + K0; if (kn >= NKT) kn -= NKT;
      a0 = *(const f16x8*)(Ab + kn*32 + lhi*8);
      stageB8(wb1, (char*)bufB, kn, wv, lane);
    }
  }
  stageB8(wb2, (char*)bufB, K0, wv, lane);
  #pragma unroll
  for (int j=0;j<13;j++){
    int col = (ch*13+j)*16 + l15;
    float bv = (col<D)? b1s[n*D+col] : 0.f;
    #pragma unroll
    for (int rr=0;rr<4;rr++){
      float v = acc[j][rr] + bv; v = v>0.f?v:0.f;
      lact[lact_idx(rh*16+lhi*4+rr, col)] = (f16)v;
    }
  }
  LGKM0;

  // GEMM2: A from lact (same rotation)
  #pragma unroll
  for (int j=0;j<13;j++) acc[j]=Z4;
  for (int kt=0; kt<NKT; kt++){
    int ka = kt + K0; if (ka >= NKT) ka -= NKT;
    VM(0); BAR();
    f16x8 x0 = rdL(lact, rh*16 + l15, ka, lhi);
    MFMA13(x0, bufB);
    BAR();
    if (kt < NKT-1){
      int kn = kt + 1 + K0; if (kn >= NKT) kn -= NKT;
      stageB8(wb2, (char*)bufB, kn, wv, lane);
    }
  }
  // epilogue: e16 + score partials
  const float* kqp[4];
  const float* kqb = kqg + (size_t)n*NTASK*DP;
  #pragma unroll
  for (int rr=0;rr<4;rr++){
    int grow = rowbase + rh*16 + lhi*4 + rr;
    kqp[rr] = kqb + (size_t)task[grow]*DP;
  }
  float p_[4] = {0,0,0,0};
  #pragma unroll
  for (int j=0;j<13;j++){
    int col = (ch*13+j)*16 + l15;
    float bv = (col<D)? b2s[n*D+col] : 0.f;
    #pragma unroll
    for (int rr=0;rr<4;rr++){
      float v = acc[j][rr] + bv; v = v>0.f?v:0.f;
      e16[((size_t)n*NB + rowbase + rh*16+lhi*4+rr)*DP + col] = (f16)v;
      p_[rr] += v * kqp[rr][col];
    }
  }
  #pragma unroll
  for (int rr=0;rr<4;rr++){
    float p = p_[rr];
    p += __shfl_xor(p, 1, 64);
    p += __shfl_xor(p, 2, 64);
    p += __shfl_xor(p, 4, 64);
    p += __shfl_xor(p, 8, 64);
    if (l15 == 0) psum[rh*16+lhi*4+rr][ch] = p;
  }
  LGKM0; BAR();
  if (tid < 64) scores[(size_t)(rowbase + tid)*NEXP + n] = psum[tid][0] + psum[tid][1];
}

// backbone: unchanged from R15 (BM=32, BK=64 phases, x-parity rotation)
__global__ __launch_bounds__(256,2) void k_backbone(
    const f16* __restrict__ x, const f16* __restrict__ w1T, const float* __restrict__ b1,
    const f16* __restrict__ w2T, const float* __restrict__ b2, f16* __restrict__ h16)
{
  __shared__ f16 bufB[2][13*1024];
  __shared__ f16 lact[32*416];
  const int tid = threadIdx.x, lane = tid & 63, wv = tid >> 6;
  const int l15 = lane & 15, lhi = lane >> 4;
  const int rh = wv >> 1, ch = wv & 1;
  const int rowbase = blockIdx.x * 32;
  const int P0 = (blockIdx.x & 1) * 3;
  const f32x4 Z4 = {0,0,0,0};
  f32x4 acc[13];

  const f16* Ab = x + (size_t)(rowbase + rh*16 + l15)*64;

  #pragma unroll
  for (int j=0;j<13;j++) acc[j]=Z4;
  STAGE_W((const char*)w1T, bufB, 0, 1);
  f16x8 a0 = *(const f16x8*)(Ab + lhi*8);
  f16x8 a1 = *(const f16x8*)(Ab + 32 + lhi*8);
  VM(0); BAR();
  MFMA13(a0, bufB[0]);
  MFMA13(a1, bufB[1]);
  BAR();
  { int pa0 = P0; STAGE_W((const char*)w2T, bufB, pa0, pa0 != 6); }
  #pragma unroll
  for (int j=0;j<13;j++){
    int col = (ch*13+j)*16 + l15;
    float bv = (col<D)? b1[col] : 0.f;
    #pragma unroll
    for (int rr=0;rr<4;rr++){
      float v = acc[j][rr] + bv; v = v>0.f?v:0.f;
      lact[lact_idx(rh*16+lhi*4+rr, col)] = (f16)v;
    }
  }
  LGKM0;

  #pragma unroll
  for (int j=0;j<13;j++) acc[j]=Z4;
  for (int p=0; p<7; p++){
    int pa = p + P0; if (pa >= 7) pa -= 7;
    VM(0); BAR();
    f16x8 x0 = rdL(lact, rh*16 + l15, 2*pa, lhi);
    MFMA13(x0, bufB[0]);
    if (pa != 6){
      f16x8 x1 = rdL(lact, rh*16 + l15, 2*pa+1, lhi);
      MFMA13(x1, bufB[1]);
    }
    BAR();
    if (p < 6){
      int pn = p + 1 + P0; if (pn >= 7) pn -= 7;
      STAGE_W((const char*)w2T, bufB, pn, pn != 6);
    }
  }
  #pragma unroll
  for (int j=0;j<13;j++){
    int col = (ch*13+j)*16 + l15;
    float bv = (col<D)? b2[col] : 0.f;
    #pragma unroll
    for (int rr=0;rr<4;rr++){
      float v = acc[j][rr] + bv; v = v>0.f?v:0.f;
      h16[(size_t)(rowbase + rh*16+lhi*4+rr)*DP + col] = (f16)v;
    }
  }
}

// attn: 512 thr = 8 waves of 16 rows (rg 0..3, cg 0..1); same footprint/sync as R15.
__global__ __launch_bounds__(512,2) void k_attn(
    const f16* __restrict__ e16, const f16* __restrict__ valT,
    const float* __restrict__ scores, f16* __restrict__ ti16)
{
  __shared__ f16 buf[2][7*1024];
  __shared__ float wsm[64*NEXP];
  const int tid = threadIdx.x, lane = tid & 63, wv = tid >> 6;   // wv 0..7
  const int l15 = lane & 15, lhi = lane >> 4;
  const int rg = wv >> 1, cg = wv & 1;                           // rg 0..3 (16 rows)
  const int cb = blockIdx.x;
  const int rowbase = blockIdx.y * 64;
  const int nd = cb ? 6 : 7;
  const int ntw = cb ? 6 : 7;
  const int t0 = cb * 14;
  const int S0 = ((blockIdx.x + blockIdx.y) & 1) * 28;
  const f32x4 Z4 = {0,0,0,0};
  f32x4 acc[7];
  #pragma unroll
  for (int j=0;j<7;j++) acc[j]=Z4;

  if (tid < 64){
    const float* sr = scores + (size_t)(rowbase + tid)*NEXP;
    float s[8]; float m = -1e30f;
    #pragma unroll
    for (int k=0;k<8;k++){ s[k]=sr[k]; m = fmaxf(m, s[k]); }
    float sum = 0.f;
    #pragma unroll
    for (int k=0;k<8;k++){ s[k] = expf(s[k]-m); sum += s[k]; }
    float inv = 1.f/sum;
    #pragma unroll
    for (int k=0;k<8;k++) wsm[tid*NEXP + k] = s[k]*inv;
  }

  #define STAGE_A(n_, p_) do {                                                  \
    const char* vb_ = (const char*)(valT + (size_t)(n_)*DP*DP);                 \
    int nu_ = nd*2, tot_ = ((p_)<6) ? nd*4 : nd*2;                              \
    for (int u = wv; u < tot_; u += 8){                                         \
      int kh_ = (u >= nu_) ? 1 : 0, uu_ = u - (kh_ ? nu_ : 0);                  \
      stage_duo(vb_, (char*)buf[kh_], 2*(p_)+kh_, t0, uu_>>1, uu_&1, lane);     \
    }                                                                           \
  } while(0)

  #define LDA_A(n_, kt_) \
    (*(const f16x8*)(e16 + ((size_t)(n_)*NB + rowbase + rg*16 + l15)*DP + (kt_)*32 + lhi*8))

  const int nS = S0 / 7;
  STAGE_A(nS, 0);
  f16x8 aC0 = LDA_A(nS,0);
  f16x8 aC1 = LDA_A(nS,1);
  LGKM0;                                   // wsm drained; loop-top BAR publishes

  for (int s=0;s<NEXP*7;s++){
    int sa = s + S0; if (sa >= NEXP*7) sa -= NEXP*7;
    int n = sa / 7, p = sa % 7;
    VM(0); BAR();
    f16 w0 = (f16)wsm[(rg*16 + l15)*NEXP + n];
    {
      f16x8 as0 = scale8(aC0, w0);
      __builtin_amdgcn_s_setprio(1);
      #pragma unroll
      for (int j=0;j<7;j++) if (j<ntw){
        int tl = cg*ntw + j;
        f16x8 b = rdB(buf[0], tl>>1, tl&1, lhi, l15);
        acc[j] = mfma16x32(as0, b, acc[j]);
      }
      __builtin_amdgcn_s_setprio(0);
    }
    if (p < 6){
      f16x8 as1 = scale8(aC1, w0);
      __builtin_amdgcn_s_setprio(1);
      #pragma unroll
      for (int j=0;j<7;j++) if (j<ntw){
        int tl = cg*ntw + j;
        f16x8 b = rdB(buf[1], tl>>1, tl&1, lhi, l15);
        acc[j] = mfma16x32(as1, b, acc[j]);
      }
      __builtin_amdgcn_s_setprio(0);
    }
    BAR();
    if (s < NEXP*7 - 1){
      int sa2 = sa + 1; if (sa2 >= NEXP*7) sa2 -= NEXP*7;
      int n2 = sa2 / 7, p2 = sa2 % 7;
      STAGE_A(n2, p2);
      aC0 = LDA_A(n2, 2*p2);
      if (p2 < 6) aC1 = LDA_A(n2, 2*p2+1);
    }
  }
  #pragma unroll
  for (int j=0;j<7;j++) if (j<ntw){
    int col = (t0 + cg*ntw + j)*16 + l15;
    #pragma unroll
    for (int rr=0;rr<4;rr++)
      ti16[(size_t)(rowbase + rg*16 + lhi*4 + rr)*DP + col] = (f16)acc[j][rr];
  }
}

// mlp3: unchanged from R15
__global__ __launch_bounds__(256,2) void k_mlp3(
    const f16* __restrict__ ti16,
    const f16* __restrict__ tw1T, const float* __restrict__ tb1,
    const f16* __restrict__ tw2T, const float* __restrict__ tb2,
    const float* __restrict__ tw3, const float* __restrict__ tb3,
    float* __restrict__ out)
{
  __shared__ f16 bufB[2][13*1024];
  __shared__ f16 lact[32*416];
  float (*psum)[2] = (float(*)[2])lact;
  const int tid = threadIdx.x, lane = tid & 63, wv = tid >> 6;
  const int l15 = lane & 15, lhi = lane >> 4;
  const int rh = wv >> 1, ch = wv & 1;
  const int rowbase = blockIdx.x * 32;
  const int P0 = (blockIdx.x & 1) * 3;
  const f32x4 Z4 = {0,0,0,0};
  f32x4 acc[13];

  const f16* Ab = ti16 + (size_t)(rowbase + rh*16 + l15)*DP;

  #pragma unroll
  for (int j=0;j<13;j++) acc[j]=Z4;
  STAGE_W((const char*)tw1T, bufB, P0, P0 != 6);
  f16x8 a0 = *(const f16x8*)(Ab + (2*P0)*32 + lhi*8);
  f16x8 a1 = (P0 != 6) ? *(const f16x8*)(Ab + (2*P0+1)*32 + lhi*8) : a0;
  for (int p=0; p<7; p++){
    int pa = p + P0; if (pa >= 7) pa -= 7;
    VM(0); BAR();
    MFMA13(a0, bufB[0]);
    if (pa != 6) MFMA13(a1, bufB[1]);
    BAR();
    if (p < 6){
      int pn = p + 1 + P0; if (pn >= 7) pn -= 7;
      STAGE_W((const char*)tw1T, bufB, pn, pn != 6);
      a0 = *(const f16x8*)(Ab + (2*pn)*32 + lhi*8);
      if (pn != 6) a1 = *(const f16x8*)(Ab + (2*pn+1)*32 + lhi*8);
    }
  }
  { int pa0 = P0; STAGE_W((const char*)tw2T, bufB, pa0, pa0 != 6); }
  #pragma unroll
  for (int j=0;j<13;j++){
    int col = (ch*13+j)*16 + l15;
    float bv = (col<D)? tb1[col] : 0.f;
    #pragma unroll
    for (int rr=0;rr<4;rr++){
      float v = acc[j][rr] + bv; v = v>0.f?v:0.f;
      lact[lact_idx(rh*16+lhi*4+rr, col)] = (f16)v;
    }
  }
  LGKM0;

  #pragma unroll
  for (int j=0;j<13;j++) acc[j]=Z4;
  for (int p=0; p<7; p++){
    int pa = p + P0; if (pa >= 7) pa -= 7;
    VM(0); BAR();
    f16x8 x0 = rdL(lact, rh*16 + l15, 2*pa, lhi);
    MFMA13(x0, bufB[0]);
    if (pa != 6){
      f16x8 x1 = rdL(lact, rh*16 + l15, 2*pa+1, lhi);
      MFMA13(x1, bufB[1]);
    }
    BAR();
    if (p < 6){
      int pn = p + 1 + P0; if (pn >= 7) pn -= 7;
      STAGE_W((const char*)tw2T, bufB, pn, pn != 6);
    }
  }
  float p_[4] = {0,0,0,0};
  #pragma unroll
  for (int j=0;j<13;j++){
    int col = (ch*13+j)*16 + l15;
    float bv = (col<D)? tb2[col] : 0.f;
    float w3 = (col<D)? tw3[col] : 0.f;
    #pragma unroll
    for (int rr=0;rr<4;rr++){
      float v = acc[j][rr] + bv; v = v>0.f?v:0.f;
      p_[rr] += v * w3;
    }
  }
  #pragma unroll
  for (int rr=0;rr<4;rr++){
    float p = p_[rr];
    p += __shfl_xor(p, 1, 64);
    p += __shfl_xor(p, 2, 64);
    p += __shfl_xor(p, 4, 64);
    p += __shfl_xor(p, 8, 64);
    if (l15 == 0) psum[rh*16+lhi*4+rr][ch] = p;
  }
  LGKM0; BAR();
  if (tid < 32) out[rowbase + tid] = psum[tid][0] + psum[tid][1] + tb3[0];
}

// ---------------- launcher ----------------

extern "C" void kernel_launch(void* const* d_in, const int* in_sizes, int n_in,
                              void* d_out, int out_size, void* d_ws, size_t ws_size,
                              hipStream_t stream)
{
  const float* obs     = (const float*)d_in[0];
  const float* act     = (const float*)d_in[1];
  const int*   task    = (const int*)  d_in[2];
  const float* bb_w1   = (const float*)d_in[3];
  const float* bb_b1   = (const float*)d_in[4];
  const float* bb_w2   = (const float*)d_in[5];
  const float* bb_b2   = (const float*)d_in[6];
  const float* ex_w1   = (const float*)d_in[7];
  const float* ex_b1   = (const float*)d_in[8];
  const float* ex_w2   = (const float*)d_in[9];
  const float* ex_b2   = (const float*)d_in[10];
  const float* key_mat = (const float*)d_in[11];
  const float* val_mat = (const float*)d_in[12];
  const float* tq      = (const float*)d_in[13];
  const float* tw_w1   = (const float*)d_in[14];
  const float* tw_b1   = (const float*)d_in[15];
  const float* tw_w2   = (const float*)d_in[16];
  const float* tw_b2   = (const float*)d_in[17];
  const float* tw_w3   = (const float*)d_in[18];
  const float* tw_b3   = (const float*)d_in[19];

  char* ws = (char*)d_ws;
  size_t off = 0;
  auto alloc = [&](size_t bytes){ void* p = ws + off; off += (bytes + 255) & ~(size_t)255; return p; };
  f16*   x16   = (f16*)  alloc((size_t)NB*64*2);
  f16*   h16   = (f16*)  alloc((size_t)NB*DP*2);
  f16*   e16   = (f16*)  alloc((size_t)NEXP*NB*DP*2);
  f16*   ti16  = (f16*)  alloc((size_t)NB*DP*2);
  float* scors = (float*)alloc((size_t)NB*NEXP*4);
  float* kq    = (float*)alloc((size_t)NEXP*NTASK*DP*4);
  f16*   bbw1T = (f16*)  alloc((size_t)DP*DP*2);
  f16*   bbw2T = (f16*)  alloc((size_t)DP*DP*2);
  f16*   exw1T = (f16*)  alloc((size_t)NEXP*DP*DP*2);
  f16*   exw2T = (f16*)  alloc((size_t)NEXP*DP*DP*2);
  f16*   valT  = (f16*)  alloc((size_t)NEXP*DP*DP*2);
  f16*   tw1T  = (f16*)  alloc((size_t)DP*DP*2);
  f16*   tw2T  = (f16*)  alloc((size_t)DP*DP*2);
  (void)ws_size; (void)in_sizes; (void)n_in; (void)out_size;

  k_build_x<<<NB*64/256, 256, 0, stream>>>(obs, act, x16);
  k_transpose_all<<<dim3(13,13,20), 256, 0, stream>>>(
      bb_w1, bb_w2, ex_w1, ex_w2, tw_w1, tw_w2,
      bbw1T, bbw2T, exw1T, exw2T, tw1T, tw2T);
  k_val_pad<<<(NEXP*DP*DP + 255)/256, 256, 0, stream>>>(val_mat, valT);
  k_kq<<<dim3(NEXP, 13), 256, 0, stream>>>(key_mat, tq, kq);

  k_backbone<<<NB/32, 256, 0, stream>>>(x16, bbw1T, bb_b1, bbw2T, bb_b2, h16);
  k_experts<<<dim3(NEXP, NB/64), 512, 0, stream>>>(h16, exw1T, ex_b1, exw2T, ex_b2,
                                                   e16, kq, task, scors);
  k_attn<<<dim3(2, NB/64), 512, 0, stream>>>(e16, valT, scors, ti16);
  k_mlp3<<<NB/32, 256, 0, stream>>>(ti16, tw1T, tw_b1, tw2T, tw_b2, tw_w3, tw_b3,
                                    (float*)d_out);
}

// Round 17
// 364.149 us; speedup vs baseline: 1.1861x; 1.1861x over previous
//
#include <hip/hip_runtime.h>

typedef _Float16 f16;
typedef f16 f16x8 __attribute__((ext_vector_type(8)));
typedef float f32x4 __attribute__((ext_vector_type(4)));

#define NB 16384
#define D 400
#define DP 416
#define NEXP 8
#define NTASK 10
#define NKT 13

#define MEMFENCE asm volatile("" ::: "memory")
#define BAR() do{ MEMFENCE; __builtin_amdgcn_s_barrier(); MEMFENCE; }while(0)
#define VM(N) asm volatile("s_waitcnt vmcnt(" #N ")" ::: "memory")
#define LGKM0 asm volatile("s_waitcnt lgkmcnt(0)" ::: "memory")

static __device__ __forceinline__ f32x4 mfma16x32(f16x8 a, f16x8 b, f32x4 c){
  return __builtin_amdgcn_mfma_f32_16x16x32_f16(a, b, c, 0, 0, 0);
}
static __device__ __forceinline__ void g2l(const void* g, void* l){
  __builtin_amdgcn_global_load_lds((const __attribute__((address_space(1))) void*)g,
      (__attribute__((address_space(3))) void*)l, 16, 0, 0);
}
static __device__ __forceinline__ f16x8 scale8(f16x8 a, f16 s){
  f16x8 r;
  #pragma unroll
  for (int e=0;e<8;e++) r[e] = a[e]*s;
  return r;
}

// ---- duo staging (verified R4/R6/R9/R10): 2 adjacent 16-col tiles for one kt,
// [16 rows][128B], chunk ^= row&7; LDS dest linear, global source pre-swizzled.
static __device__ __forceinline__ void stage_duo(const char* wbase, char* lds, int kt,
                                                 int t0, int dd, int h, int lane){
  const int r = lane >> 3, c = lane & 7, cg = c ^ r;
  g2l(wbase + (size_t)((t0 + dd*2 + (cg>>2))*16 + h*8 + r)*832 + (size_t)kt*64 + (cg&3)*16,
      lds + dd*2048 + h*1024);
}
static __device__ __forceinline__ f16x8 rdB(const f16* buf, int dloc, int t, int lhi, int l15){
  return *(const f16x8*)(buf + dloc*1024 + l15*64 + ((((t*4+lhi) ^ (l15&7)))<<3));
}
// lact: [rows][416] f16, 16B-chunk XOR swizzle on chunks<48
static __device__ __forceinline__ f16x8 rdL(const f16* lact, int r, int kt, int lhi){
  int q = kt*4 + lhi;
  int c = (q < 48) ? (q ^ (r&7)) : q;
  return *(const f16x8*)(lact + r*416 + (c<<3));
}
static __device__ __forceinline__ int lact_idx(int r, int col){
  int q = col >> 3;
  int c = (q < 48) ? (q ^ (r&7)) : q;
  return r*416 + (c<<3) + (col&7);
}
// full-width 416-col staging for one kt: 26 units of 1KB over 4 waves
static __device__ __forceinline__ void stageB4(const char* wb, char* buf, int kt,
                                               int wv, int lane){
  for (int u = wv; u < 26; u += 4) stage_duo(wb, buf, kt, 0, u>>1, u&1, lane);
}

// ---------------- prep kernels ----------------

__global__ void k_build_x(const float* __restrict__ obs, const float* __restrict__ act,
                          f16* __restrict__ x)
{
  int idx = blockIdx.x*256 + threadIdx.x;
  int b = idx >> 6, c = idx & 63;
  float v = 0.f;
  if (c < 39) v = obs[b*39 + c];
  else if (c < 43) v = act[b*4 + (c - 39)];
  x[idx] = (f16)v;
}

__global__ void k_transpose_all(
    const float* __restrict__ bb_w1, const float* __restrict__ bb_w2,
    const float* __restrict__ ex_w1, const float* __restrict__ ex_w2,
    const float* __restrict__ tw_w1, const float* __restrict__ tw_w2,
    f16* __restrict__ bbw1T, f16* __restrict__ bbw2T,
    f16* __restrict__ exw1T, f16* __restrict__ exw2T,
    f16* __restrict__ tw1T,  f16* __restrict__ tw2T)
{
  __shared__ float t[32][33];
  const int z = blockIdx.z;
  const float* in; f16* out; int K = D;
  if (z == 0){ in = bb_w1; out = bbw1T; K = 43; }
  else if (z == 1){ in = bb_w2; out = bbw2T; }
  else if (z < 10){ in = ex_w1 + (size_t)(z-2)*D*D;  out = exw1T + (size_t)(z-2)*DP*DP; }
  else if (z < 18){ in = ex_w2 + (size_t)(z-10)*D*D; out = exw2T + (size_t)(z-10)*DP*DP; }
  else if (z == 18){ in = tw_w1; out = tw1T; }
  else { in = tw_w2; out = tw2T; }
  int tx = threadIdx.x & 31, ty = threadIdx.x >> 5;
  int n0 = blockIdx.x*32, k0 = blockIdx.y*32;
  #pragma unroll
  for (int r=0;r<4;r++){
    int k = k0 + ty + r*8, nn = n0 + tx;
    t[ty + r*8][tx] = (k < K && nn < D) ? in[(size_t)k*D + nn] : 0.f;
  }
  __syncthreads();
  #pragma unroll
  for (int r=0;r<4;r++){
    int nn = n0 + ty + r*8, kp = k0 + tx;
    if (nn < DP && kp < DP) out[(size_t)nn*DP + kp] = (f16)t[tx][ty + r*8];
  }
}

__global__ void k_val_pad(const float* __restrict__ in, f16* __restrict__ out)
{
  int idx = blockIdx.x*256 + threadIdx.x;
  if (idx >= NEXP*DP*DP) return;
  int c = idx % DP, r = (idx / DP) % DP, n = idx / (DP*DP);
  float v = (r < D && c < D) ? in[((size_t)n*D + r)*D + c] : 0.f;
  out[idx] = (f16)v;
}

// kq: col-split grid (NEXP, 13); km column panel staged in LDS. (verified R12)
__global__ void k_kq(const float* __restrict__ key_mat, const float* __restrict__ tq,
                     float* __restrict__ kq)
{
  __shared__ float kcol[D*32];
  __shared__ float tqs[NTASK*D];
  const int n = blockIdx.x, cb = blockIdx.y, tid = threadIdx.x;
  const int c0 = cb*32;
  const float* km = key_mat + (size_t)n*D*D;
  for (int idx=tid; idx<NTASK*D; idx+=256) tqs[idx] = tq[idx];
  for (int idx=tid; idx<D*32; idx+=256){
    int i = idx>>5, c = idx&31;
    int col = c0 + c;
    kcol[idx] = (col < D) ? km[(size_t)i*D + col] : 0.f;
  }
  __syncthreads();
  const int c = tid & 31, tg = tid >> 5;
  #pragma unroll
  for (int rep=0; rep<2; rep++){
    int t = tg + rep*8;
    if (t < NTASK){
      float acc = 0.f;
      for (int i=0;i<D;i++) acc += kcol[i*32+c] * tqs[t*D+i];
      int col = c0 + c;
      if (col < DP) kq[((size_t)n*NTASK + t)*DP + col] = acc;
    }
  }
}

// ---------------- compute kernels ----------------

#define MFMA26(a0_, a1_, BUF) do {                                              \
    __builtin_amdgcn_s_setprio(1);                                              \
    _Pragma("unroll")                                                           \
    for (int j=0;j<13;j++){                                                     \
      int tj = ch*13 + j;                                                       \
      f16x8 b = rdB((BUF), tj>>1, tj&1, lhi, l15);                              \
      acc[0][j] = mfma16x32((a0_), b, acc[0][j]);                               \
      acc[1][j] = mfma16x32((a1_), b, acc[1][j]);                               \
    }                                                                           \
    __builtin_amdgcn_s_setprio(0);                                              \
  } while(0)

#define MFMA13(a0_, BUF) do {                                                   \
    __builtin_amdgcn_s_setprio(1);                                              \
    _Pragma("unroll")                                                           \
    for (int j=0;j<13;j++){                                                     \
      int tj = ch*13 + j;                                                       \
      f16x8 b = rdB((BUF), tj>>1, tj&1, lhi, l15);                              \
      acc[j] = mfma16x32((a0_), b, acc[j]);                                     \
    }                                                                           \
    __builtin_amdgcn_s_setprio(0);                                              \
  } while(0)

// BK=64 staging over 4 waves: kh-major 26+26 units; half phase = 26 (kh0 only).
#define STAGE_W(wb_, buf_, p_, full_) do{                                       \
    int tot_ = (full_) ? 52 : 26;                                               \
    for (int u = wv; u < tot_; u += 4){                                         \
      int kh_ = (u >= 26) ? 1 : 0, uu_ = u - (kh_ ? 26 : 0);                    \
      stage_duo((wb_), (char*)(buf_)[kh_], 2*(p_)+kh_, 0, uu_>>1, uu_&1, lane); \
    }                                                                           \
  } while(0)

// experts: R15 champion form — BM=64, 4 waves (26 MFMA/wave/phase), lact,
// 2 blocks/CU, VM(0) 2-barrier, K-rotation keyed (bx+by)&1.
__global__ __launch_bounds__(256,2) void k_experts(
    const f16* __restrict__ h16, const f16* __restrict__ w1T, const float* __restrict__ b1s,
    const f16* __restrict__ w2T, const float* __restrict__ b2s,
    f16* __restrict__ e16, const float* __restrict__ kqg, const int* __restrict__ task,
    float* __restrict__ scores)
{
  __shared__ f16 bufB[13*1024];
  __shared__ f16 lact[64*416];
  float (*psum)[2] = (float(*)[2])lact;
  const int tid = threadIdx.x, lane = tid & 63, wv = tid >> 6;
  const int l15 = lane & 15, lhi = lane >> 4;
  const int rh = wv >> 1, ch = wv & 1;
  const int n = blockIdx.x;
  const int rowbase = blockIdx.y * 64;
  const int K0 = ((blockIdx.x + blockIdx.y) & 1) * 7;
  const f32x4 Z4 = {0,0,0,0};
  f32x4 acc[2][13];

  const char* wb1 = (const char*)(w1T + (size_t)n*DP*DP);
  const char* wb2 = (const char*)(w2T + (size_t)n*DP*DP);
  const f16* Ab = h16 + (size_t)(rowbase + rh*32 + l15)*DP;

  // GEMM1 (kt order rotated: K0, K0+1, ..., wrap)
  #pragma unroll
  for (int j=0;j<13;j++){ acc[0][j]=Z4; acc[1][j]=Z4; }
  f16x8 a0 = *(const f16x8*)(Ab + K0*32 + lhi*8);
  f16x8 a1 = *(const f16x8*)(Ab + 16*DP + K0*32 + lhi*8);
  stageB4(wb1, (char*)bufB, K0, wv, lane);
  for (int kt=0; kt<NKT; kt++){
    VM(0); BAR();
    MFMA26(a0, a1, bufB);
    BAR();
    if (kt < NKT-1){
      int kn = kt + 1 + K0; if (kn >= NKT) kn -= NKT;
      a0 = *(const f16x8*)(Ab + kn*32 + lhi*8);
      a1 = *(const f16x8*)(Ab + 16*DP + kn*32 + lhi*8);
      stageB4(wb1, (char*)bufB, kn, wv, lane);
    }
  }
  stageB4(wb2, (char*)bufB, K0, wv, lane);
  #pragma unroll
  for (int j=0;j<13;j++){
    int col = (ch*13+j)*16 + l15;
    float bv = (col<D)? b1s[n*D+col] : 0.f;
    #pragma unroll
    for (int ar=0;ar<2;ar++)
      #pragma unroll
      for (int rr=0;rr<4;rr++){
        float v = acc[ar][j][rr] + bv; v = v>0.f?v:0.f;
        lact[lact_idx(rh*32+ar*16+lhi*4+rr, col)] = (f16)v;
      }
  }
  LGKM0;

  // GEMM2: A from lact (same rotation)
  #pragma unroll
  for (int j=0;j<13;j++){ acc[0][j]=Z4; acc[1][j]=Z4; }
  for (int kt=0; kt<NKT; kt++){
    int ka = kt + K0; if (ka >= NKT) ka -= NKT;
    VM(0); BAR();
    f16x8 x0 = rdL(lact, rh*32 + l15, ka, lhi);
    f16x8 x1 = rdL(lact, rh*32 + 16 + l15, ka, lhi);
    MFMA26(x0, x1, bufB);
    BAR();
    if (kt < NKT-1){
      int kn = kt + 1 + K0; if (kn >= NKT) kn -= NKT;
      stageB4(wb2, (char*)bufB, kn, wv, lane);
    }
  }
  // epilogue: e16 + score partials
  const float* kqp[2][4];
  const float* kqb = kqg + (size_t)n*NTASK*DP;
  #pragma unroll
  for (int ar=0;ar<2;ar++)
    #pragma unroll
    for (int rr=0;rr<4;rr++){
      int grow = rowbase + rh*32 + ar*16 + lhi*4 + rr;
      kqp[ar][rr] = kqb + (size_t)task[grow]*DP;
    }
  float p_[2][4] = {{0,0,0,0},{0,0,0,0}};
  #pragma unroll
  for (int j=0;j<13;j++){
    int col = (ch*13+j)*16 + l15;
    float bv = (col<D)? b2s[n*D+col] : 0.f;
    #pragma unroll
    for (int ar=0;ar<2;ar++)
      #pragma unroll
      for (int rr=0;rr<4;rr++){
        float v = acc[ar][j][rr] + bv; v = v>0.f?v:0.f;
        e16[((size_t)n*NB + rowbase + rh*32+ar*16+lhi*4+rr)*DP + col] = (f16)v;
        p_[ar][rr] += v * kqp[ar][rr][col];
      }
  }
  #pragma unroll
  for (int ar=0;ar<2;ar++)
    #pragma unroll
    for (int rr=0;rr<4;rr++){
      float p = p_[ar][rr];
      p += __shfl_xor(p, 1, 64);
      p += __shfl_xor(p, 2, 64);
      p += __shfl_xor(p, 4, 64);
      p += __shfl_xor(p, 8, 64);
      if (l15 == 0) psum[rh*32+ar*16+lhi*4+rr][ch] = p;
    }
  LGKM0; BAR();
  if (tid < 64) scores[(size_t)(rowbase + tid)*NEXP + n] = psum[tid][0] + psum[tid][1];
}

// backbone: BM=32, BK=64 phases, 2 blocks/CU, GEMM2 rotated by x-parity
__global__ __launch_bounds__(256,2) void k_backbone(
    const f16* __restrict__ x, const f16* __restrict__ w1T, const float* __restrict__ b1,
    const f16* __restrict__ w2T, const float* __restrict__ b2, f16* __restrict__ h16)
{
  __shared__ f16 bufB[2][13*1024];
  __shared__ f16 lact[32*416];
  const int tid = threadIdx.x, lane = tid & 63, wv = tid >> 6;
  const int l15 = lane & 15, lhi = lane >> 4;
  const int rh = wv >> 1, ch = wv & 1;
  const int rowbase = blockIdx.x * 32;
  const int P0 = (blockIdx.x & 1) * 3;
  const f32x4 Z4 = {0,0,0,0};
  f32x4 acc[13];

  const f16* Ab = x + (size_t)(rowbase + rh*16 + l15)*64;

  // GEMM1: K=64 = one full phase
  #pragma unroll
  for (int j=0;j<13;j++) acc[j]=Z4;
  STAGE_W((const char*)w1T, bufB, 0, 1);
  f16x8 a0 = *(const f16x8*)(Ab + lhi*8);
  f16x8 a1 = *(const f16x8*)(Ab + 32 + lhi*8);
  VM(0); BAR();
  MFMA13(a0, bufB[0]);
  MFMA13(a1, bufB[1]);
  BAR();
  { int pa0 = P0; STAGE_W((const char*)w2T, bufB, pa0, pa0 != 6); }
  #pragma unroll
  for (int j=0;j<13;j++){
    int col = (ch*13+j)*16 + l15;
    float bv = (col<D)? b1[col] : 0.f;
    #pragma unroll
    for (int rr=0;rr<4;rr++){
      float v = acc[j][rr] + bv; v = v>0.f?v:0.f;
      lact[lact_idx(rh*16+lhi*4+rr, col)] = (f16)v;
    }
  }
  LGKM0;

  // GEMM2: 7 ragged BK=64 phases, rotated
  #pragma unroll
  for (int j=0;j<13;j++) acc[j]=Z4;
  for (int p=0; p<7; p++){
    int pa = p + P0; if (pa >= 7) pa -= 7;
    VM(0); BAR();
    f16x8 x0 = rdL(lact, rh*16 + l15, 2*pa, lhi);
    MFMA13(x0, bufB[0]);
    if (pa != 6){
      f16x8 x1 = rdL(lact, rh*16 + l15, 2*pa+1, lhi);
      MFMA13(x1, bufB[1]);
    }
    BAR();
    if (p < 6){
      int pn = p + 1 + P0; if (pn >= 7) pn -= 7;
      STAGE_W((const char*)w2T, bufB, pn, pn != 6);
    }
  }
  #pragma unroll
  for (int j=0;j<13;j++){
    int col = (ch*13+j)*16 + l15;
    float bv = (col<D)? b2[col] : 0.f;
    #pragma unroll
    for (int rr=0;rr<4;rr++){
      float v = acc[j][rr] + bv; v = v>0.f?v:0.f;
      h16[(size_t)(rowbase + rh*16+lhi*4+rr)*DP + col] = (f16)v;
    }
  }
}

// attn: BM=64, col-halves, 56 BK=64 phases flattened; rotation keyed (bx+by)&1.
__global__ __launch_bounds__(256,2) void k_attn(
    const f16* __restrict__ e16, const f16* __restrict__ valT,
    const float* __restrict__ scores, f16* __restrict__ ti16)
{
  __shared__ f16 buf[2][7*1024];
  __shared__ float wsm[64*NEXP];
  const int tid = threadIdx.x, lane = tid & 63, wv = tid >> 6;
  const int l15 = lane & 15, lhi = lane >> 4;
  const int rg = wv >> 1, cg = wv & 1;
  const int cb = blockIdx.x;
  const int rowbase = blockIdx.y * 64;
  const int nd = cb ? 6 : 7;
  const int ntw = cb ? 6 : 7;
  const int t0 = cb * 14;
  const int S0 = ((blockIdx.x + blockIdx.y) & 1) * 28;
  const f32x4 Z4 = {0,0,0,0};
  f32x4 acc[2][7];
  #pragma unroll
  for (int a=0;a<2;a++)
    #pragma unroll
    for (int j=0;j<7;j++) acc[a][j]=Z4;

  if (tid < 64){
    const float* sr = scores + (size_t)(rowbase + tid)*NEXP;
    float s[8]; float m = -1e30f;
    #pragma unroll
    for (int k=0;k<8;k++){ s[k]=sr[k]; m = fmaxf(m, s[k]); }
    float sum = 0.f;
    #pragma unroll
    for (int k=0;k<8;k++){ s[k] = expf(s[k]-m); sum += s[k]; }
    float inv = 1.f/sum;
    #pragma unroll
    for (int k=0;k<8;k++) wsm[tid*NEXP + k] = s[k]*inv;
  }

  #define STAGE_A(n_, p_) do {                                                  \
    const char* vb_ = (const char*)(valT + (size_t)(n_)*DP*DP);                 \
    int nu_ = nd*2, tot_ = ((p_)<6) ? nd*4 : nd*2;                              \
    for (int u = wv; u < tot_; u += 4){                                         \
      int kh_ = (u >= nu_) ? 1 : 0, uu_ = u - (kh_ ? nu_ : 0);                  \
      stage_duo(vb_, (char*)buf[kh_], 2*(p_)+kh_, t0, uu_>>1, uu_&1, lane);     \
    }                                                                           \
  } while(0)

  #define LDA_A(n_, kt_, ar_) \
    (*(const f16x8*)(e16 + ((size_t)(n_)*NB + rowbase + rg*32 + (ar_)*16 + l15)*DP + (kt_)*32 + lhi*8))

  const int nS = S0 / 7;
  STAGE_A(nS, 0);
  f16x8 aC00 = LDA_A(nS,0,0), aC01 = LDA_A(nS,0,1);
  f16x8 aC10 = LDA_A(nS,1,0), aC11 = LDA_A(nS,1,1);
  LGKM0;

  for (int s=0;s<NEXP*7;s++){
    int sa = s + S0; if (sa >= NEXP*7) sa -= NEXP*7;
    int n = sa / 7, p = sa % 7;
    VM(0); BAR();
    f16 w0 = (f16)wsm[(rg*32      + l15)*NEXP + n];
    f16 w1 = (f16)wsm[(rg*32 + 16 + l15)*NEXP + n];
    {
      f16x8 as0 = scale8(aC00, w0), as1 = scale8(aC01, w1);
      __builtin_amdgcn_s_setprio(1);
      #pragma unroll
      for (int j=0;j<7;j++) if (j<ntw){
        int tl = cg*ntw + j;
        f16x8 b = rdB(buf[0], tl>>1, tl&1, lhi, l15);
        acc[0][j] = mfma16x32(as0, b, acc[0][j]);
        acc[1][j] = mfma16x32(as1, b, acc[1][j]);
      }
      __builtin_amdgcn_s_setprio(0);
    }
    if (p < 6){
      f16x8 as0 = scale8(aC10, w0), as1 = scale8(aC11, w1);
      __builtin_amdgcn_s_setprio(1);
      #pragma unroll
      for (int j=0;j<7;j++) if (j<ntw){
        int tl = cg*ntw + j;
        f16x8 b = rdB(buf[1], tl>>1, tl&1, lhi, l15);
        acc[0][j] = mfma16x32(as0, b, acc[0][j]);
        acc[1][j] = mfma16x32(as1, b, acc[1][j]);
      }
      __builtin_amdgcn_s_setprio(0);
    }
    BAR();
    if (s < NEXP*7 - 1){
      int sa2 = sa + 1; if (sa2 >= NEXP*7) sa2 -= NEXP*7;
      int n2 = sa2 / 7, p2 = sa2 % 7;
      STAGE_A(n2, p2);
      aC00 = LDA_A(n2, 2*p2,   0); aC01 = LDA_A(n2, 2*p2,   1);
      if (p2 < 6){ aC10 = LDA_A(n2, 2*p2+1, 0); aC11 = LDA_A(n2, 2*p2+1, 1); }
    }
  }
  #pragma unroll
  for (int ar=0;ar<2;ar++)
    #pragma unroll
    for (int j=0;j<7;j++) if (j<ntw){
      int col = (t0 + cg*ntw + j)*16 + l15;
      #pragma unroll
      for (int rr=0;rr<4;rr++)
        ti16[(size_t)(rowbase + rg*32 + ar*16 + lhi*4 + rr)*DP + col] = (f16)acc[ar][j][rr];
    }
}

// mlp3: BM=32, BK=64 (7+7 ragged phases), 2 blocks/CU, both GEMMs rotated (x-parity)
__global__ __launch_bounds__(256,2) void k_mlp3(
    const f16* __restrict__ ti16,
    const f16* __restrict__ tw1T, const float* __restrict__ tb1,
    const f16* __restrict__ tw2T, const float* __restrict__ tb2,
    const float* __restrict__ tw3, const float* __restrict__ tb3,
    float* __restrict__ out)
{
  __shared__ f16 bufB[2][13*1024];
  __shared__ f16 lact[32*416];
  float (*psum)[2] = (float(*)[2])lact;
  const int tid = threadIdx.x, lane = tid & 63, wv = tid >> 6;
  const int l15 = lane & 15, lhi = lane >> 4;
  const int rh = wv >> 1, ch = wv & 1;
  const int rowbase = blockIdx.x * 32;
  const int P0 = (blockIdx.x & 1) * 3;
  const f32x4 Z4 = {0,0,0,0};
  f32x4 acc[13];

  const f16* Ab = ti16 + (size_t)(rowbase + rh*16 + l15)*DP;

  // GEMM1 (rotated)
  #pragma unroll
  for (int j=0;j<13;j++) acc[j]=Z4;
  STAGE_W((const char*)tw1T, bufB, P0, P0 != 6);
  f16x8 a0 = *(const f16x8*)(Ab + (2*P0)*32 + lhi*8);
  f16x8 a1 = (P0 != 6) ? *(const f16x8*)(Ab + (2*P0+1)*32 + lhi*8) : a0;
  for (int p=0; p<7; p++){
    int pa = p + P0; if (pa >= 7) pa -= 7;
    VM(0); BAR();
    MFMA13(a0, bufB[0]);
    if (pa != 6) MFMA13(a1, bufB[1]);
    BAR();
    if (p < 6){
      int pn = p + 1 + P0; if (pn >= 7) pn -= 7;
      STAGE_W((const char*)tw1T, bufB, pn, pn != 6);
      a0 = *(const f16x8*)(Ab + (2*pn)*32 + lhi*8);
      if (pn != 6) a1 = *(const f16x8*)(Ab + (2*pn+1)*32 + lhi*8);
    }
  }
  { int pa0 = P0; STAGE_W((const char*)tw2T, bufB, pa0, pa0 != 6); }
  #pragma unroll
  for (int j=0;j<13;j++){
    int col = (ch*13+j)*16 + l15;
    float bv = (col<D)? tb1[col] : 0.f;
    #pragma unroll
    for (int rr=0;rr<4;rr++){
      float v = acc[j][rr] + bv; v = v>0.f?v:0.f;
      lact[lact_idx(rh*16+lhi*4+rr, col)] = (f16)v;
    }
  }
  LGKM0;

  // GEMM2 (rotated)
  #pragma unroll
  for (int j=0;j<13;j++) acc[j]=Z4;
  for (int p=0; p<7; p++){
    int pa = p + P0; if (pa >= 7) pa -= 7;
    VM(0); BAR();
    f16x8 x0 = rdL(lact, rh*16 + l15, 2*pa, lhi);
    MFMA13(x0, bufB[0]);
    if (pa != 6){
      f16x8 x1 = rdL(lact, rh*16 + l15, 2*pa+1, lhi);
      MFMA13(x1, bufB[1]);
    }
    BAR();
    if (p < 6){
      int pn = p + 1 + P0; if (pn >= 7) pn -= 7;
      STAGE_W((const char*)tw2T, bufB, pn, pn != 6);
    }
  }
  // L3 dot
  float p_[4] = {0,0,0,0};
  #pragma unroll
  for (int j=0;j<13;j++){
    int col = (ch*13+j)*16 + l15;
    float bv = (col<D)? tb2[col] : 0.f;
    float w3 = (col<D)? tw3[col] : 0.f;
    #pragma unroll
    for (int rr=0;rr<4;rr++){
      float v = acc[j][rr] + bv; v = v>0.f?v:0.f;
      p_[rr] += v * w3;
    }
  }
  #pragma unroll
  for (int rr=0;rr<4;rr++){
    float p = p_[rr];
    p += __shfl_xor(p, 1, 64);
    p += __shfl_xor(p, 2, 64);
    p += __shfl_xor(p, 4, 64);
    p += __shfl_xor(p, 8, 64);
    if (l15 == 0) psum[rh*16+lhi*4+rr][ch] = p;
  }
  LGKM0; BAR();
  if (tid < 32) out[rowbase + tid] = psum[tid][0] + psum[tid][1] + tb3[0];
}

// ---------------- launcher ----------------

extern "C" void kernel_launch(void* const* d_in, const int* in_sizes, int n_in,
                              void* d_out, int out_size, void* d_ws, size_t ws_size,
                              hipStream_t stream)
{
  const float* obs     = (const float*)d_in[0];
  const float* act     = (const float*)d_in[1];
  const int*   task    = (const int*)  d_in[2];
  const float* bb_w1   = (const float*)d_in[3];
  const float* bb_b1   = (const float*)d_in[4];
  const float* bb_w2   = (const float*)d_in[5];
  const float* bb_b2   = (const float*)d_in[6];
  const float* ex_w1   = (const float*)d_in[7];
  const float* ex_b1   = (const float*)d_in[8];
  const float* ex_w2   = (const float*)d_in[9];
  const float* ex_b2   = (const float*)d_in[10];
  const float* key_mat = (const float*)d_in[11];
  const float* val_mat = (const float*)d_in[12];
  const float* tq      = (const float*)d_in[13];
  const float* tw_w1   = (const float*)d_in[14];
  const float* tw_b1   = (const float*)d_in[15];
  const float* tw_w2   = (const float*)d_in[16];
  const float* tw_b2   = (const float*)d_in[17];
  const float* tw_w3   = (const float*)d_in[18];
  const float* tw_b3   = (const float*)d_in[19];

  char* ws = (char*)d_ws;
  size_t off = 0;
  auto alloc = [&](size_t bytes){ void* p = ws + off; off += (bytes + 255) & ~(size_t)255; return p; };
  f16*   x16   = (f16*)  alloc((size_t)NB*64*2);
  f16*   h16   = (f16*)  alloc((size_t)NB*DP*2);
  f16*   e16   = (f16*)  alloc((size_t)NEXP*NB*DP*2);
  f16*   ti16  = (f16*)  alloc((size_t)NB*DP*2);
  float* scors = (float*)alloc((size_t)NB*NEXP*4);
  float* kq    = (float*)alloc((size_t)NEXP*NTASK*DP*4);
  f16*   bbw1T = (f16*)  alloc((size_t)DP*DP*2);
  f16*   bbw2T = (f16*)  alloc((size_t)DP*DP*2);
  f16*   exw1T = (f16*)  alloc((size_t)NEXP*DP*DP*2);
  f16*   exw2T = (f16*)  alloc((size_t)NEXP*DP*DP*2);
  f16*   valT  = (f16*)  alloc((size_t)NEXP*DP*DP*2);
  f16*   tw1T  = (f16*)  alloc((size_t)DP*DP*2);
  f16*   tw2T  = (f16*)  alloc((size_t)DP*DP*2);
  (void)ws_size; (void)in_sizes; (void)n_in; (void)out_size;

  k_build_x<<<NB*64/256, 256, 0, stream>>>(obs, act, x16);
  k_transpose_all<<<dim3(13,13,20), 256, 0, stream>>>(
      bb_w1, bb_w2, ex_w1, ex_w2, tw_w1, tw_w2,
      bbw1T, bbw2T, exw1T, exw2T, tw1T, tw2T);
  k_val_pad<<<(NEXP*DP*DP + 255)/256, 256, 0, stream>>>(val_mat, valT);
  k_kq<<<dim3(NEXP, 13), 256, 0, stream>>>(key_mat, tq, kq);

  k_backbone<<<NB/32, 256, 0, stream>>>(x16, bbw1T, bb_b1, bbw2T, bb_b2, h16);
  k_experts<<<dim3(NEXP, NB/64), 256, 0, stream>>>(h16, exw1T, ex_b1, exw2T, ex_b2,
                                                   e16, kq, task, scors);
  k_attn<<<dim3(2, NB/64), 256, 0, stream>>>(e16, valT, scors, ti16);
  k_mlp3<<<NB/32, 256, 0, stream>>>(ti16, tw1T, tw_b1, tw2T, tw_b2, tw_w3, tw_b3,
                                    (float*)d_out);
}

// Round 18
// 345.697 us; speedup vs baseline: 1.2494x; 1.0534x over previous
//
#include <hip/hip_runtime.h>

typedef _Float16 f16;
typedef f16 f16x8 __attribute__((ext_vector_type(8)));
typedef float f32x4 __attribute__((ext_vector_type(4)));

#define NB 16384
#define D 400
#define DP 416
#define NEXP 8
#define NTASK 10
#define NKT 13

#define MEMFENCE asm volatile("" ::: "memory")
#define BAR() do{ MEMFENCE; __builtin_amdgcn_s_barrier(); MEMFENCE; }while(0)
#define VM(N) asm volatile("s_waitcnt vmcnt(" #N ")" ::: "memory")
#define LGKM0 asm volatile("s_waitcnt lgkmcnt(0)" ::: "memory")

static __device__ __forceinline__ f32x4 mfma16x32(f16x8 a, f16x8 b, f32x4 c){
  return __builtin_amdgcn_mfma_f32_16x16x32_f16(a, b, c, 0, 0, 0);
}
static __device__ __forceinline__ void g2l(const void* g, void* l){
  __builtin_amdgcn_global_load_lds((const __attribute__((address_space(1))) void*)g,
      (__attribute__((address_space(3))) void*)l, 16, 0, 0);
}
static __device__ __forceinline__ f16x8 scale8(f16x8 a, f16 s){
  f16x8 r;
  #pragma unroll
  for (int e=0;e<8;e++) r[e] = a[e]*s;
  return r;
}

// ---- duo staging (verified R4/R6/R9/R10): 2 adjacent 16-col tiles for one kt,
// [16 rows][128B], chunk ^= row&7; LDS dest linear, global source pre-swizzled.
static __device__ __forceinline__ void stage_duo(const char* wbase, char* lds, int kt,
                                                 int t0, int dd, int h, int lane){
  const int r = lane >> 3, c = lane & 7, cg = c ^ r;
  g2l(wbase + (size_t)((t0 + dd*2 + (cg>>2))*16 + h*8 + r)*832 + (size_t)kt*64 + (cg&3)*16,
      lds + dd*2048 + h*1024);
}
static __device__ __forceinline__ f16x8 rdB(const f16* buf, int dloc, int t, int lhi, int l15){
  return *(const f16x8*)(buf + dloc*1024 + l15*64 + ((((t*4+lhi) ^ (l15&7)))<<3));
}
// lact: [rows][416] f16, 16B-chunk XOR swizzle on chunks<48
static __device__ __forceinline__ f16x8 rdL(const f16* lact, int r, int kt, int lhi){
  int q = kt*4 + lhi;
  int c = (q < 48) ? (q ^ (r&7)) : q;
  return *(const f16x8*)(lact + r*416 + (c<<3));
}
static __device__ __forceinline__ int lact_idx(int r, int col){
  int q = col >> 3;
  int c = (q < 48) ? (q ^ (r&7)) : q;
  return r*416 + (c<<3) + (col&7);
}
// full-width 416-col staging for one kt: 26 units of 1KB over 4 waves
static __device__ __forceinline__ void stageB4(const char* wb, char* buf, int kt,
                                               int wv, int lane){
  for (int u = wv; u < 26; u += 4) stage_duo(wb, buf, kt, 0, u>>1, u&1, lane);
}

// ---------------- prep kernels ----------------

__global__ void k_build_x(const float* __restrict__ obs, const float* __restrict__ act,
                          f16* __restrict__ x)
{
  int idx = blockIdx.x*256 + threadIdx.x;
  int b = idx >> 6, c = idx & 63;
  float v = 0.f;
  if (c < 39) v = obs[b*39 + c];
  else if (c < 43) v = act[b*4 + (c - 39)];
  x[idx] = (f16)v;
}

__global__ void k_transpose_all(
    const float* __restrict__ bb_w1, const float* __restrict__ bb_w2,
    const float* __restrict__ ex_w1, const float* __restrict__ ex_w2,
    const float* __restrict__ tw_w1, const float* __restrict__ tw_w2,
    f16* __restrict__ bbw1T, f16* __restrict__ bbw2T,
    f16* __restrict__ exw1T, f16* __restrict__ exw2T,
    f16* __restrict__ tw1T,  f16* __restrict__ tw2T)
{
  __shared__ float t[32][33];
  const int z = blockIdx.z;
  const float* in; f16* out; int K = D;
  if (z == 0){ in = bb_w1; out = bbw1T; K = 43; }
  else if (z == 1){ in = bb_w2; out = bbw2T; }
  else if (z < 10){ in = ex_w1 + (size_t)(z-2)*D*D;  out = exw1T + (size_t)(z-2)*DP*DP; }
  else if (z < 18){ in = ex_w2 + (size_t)(z-10)*D*D; out = exw2T + (size_t)(z-10)*DP*DP; }
  else if (z == 18){ in = tw_w1; out = tw1T; }
  else { in = tw_w2; out = tw2T; }
  int tx = threadIdx.x & 31, ty = threadIdx.x >> 5;
  int n0 = blockIdx.x*32, k0 = blockIdx.y*32;
  #pragma unroll
  for (int r=0;r<4;r++){
    int k = k0 + ty + r*8, nn = n0 + tx;
    t[ty + r*8][tx] = (k < K && nn < D) ? in[(size_t)k*D + nn] : 0.f;
  }
  __syncthreads();
  #pragma unroll
  for (int r=0;r<4;r++){
    int nn = n0 + ty + r*8, kp = k0 + tx;
    if (nn < DP && kp < DP) out[(size_t)nn*DP + kp] = (f16)t[tx][ty + r*8];
  }
}

__global__ void k_val_pad(const float* __restrict__ in, f16* __restrict__ out)
{
  int idx = blockIdx.x*256 + threadIdx.x;
  if (idx >= NEXP*DP*DP) return;
  int c = idx % DP, r = (idx / DP) % DP, n = idx / (DP*DP);
  float v = (r < D && c < D) ? in[((size_t)n*D + r)*D + c] : 0.f;
  out[idx] = (f16)v;
}

// kq: col-split grid (NEXP, 13); km column panel staged in LDS. (verified R12)
__global__ void k_kq(const float* __restrict__ key_mat, const float* __restrict__ tq,
                     float* __restrict__ kq)
{
  __shared__ float kcol[D*32];
  __shared__ float tqs[NTASK*D];
  const int n = blockIdx.x, cb = blockIdx.y, tid = threadIdx.x;
  const int c0 = cb*32;
  const float* km = key_mat + (size_t)n*D*D;
  for (int idx=tid; idx<NTASK*D; idx+=256) tqs[idx] = tq[idx];
  for (int idx=tid; idx<D*32; idx+=256){
    int i = idx>>5, c = idx&31;
    int col = c0 + c;
    kcol[idx] = (col < D) ? km[(size_t)i*D + col] : 0.f;
  }
  __syncthreads();
  const int c = tid & 31, tg = tid >> 5;
  #pragma unroll
  for (int rep=0; rep<2; rep++){
    int t = tg + rep*8;
    if (t < NTASK){
      float acc = 0.f;
      for (int i=0;i<D;i++) acc += kcol[i*32+c] * tqs[t*D+i];
      int col = c0 + c;
      if (col < DP) kq[((size_t)n*NTASK + t)*DP + col] = acc;
    }
  }
}

// ---------------- compute kernels ----------------

#define MFMA26(a0_, a1_, BUF) do {                                              \
    __builtin_amdgcn_s_setprio(1);                                              \
    _Pragma("unroll")                                                           \
    for (int j=0;j<13;j++){                                                     \
      int tj = ch*13 + j;                                                       \
      f16x8 b = rdB((BUF), tj>>1, tj&1, lhi, l15);                              \
      acc[0][j] = mfma16x32((a0_), b, acc[0][j]);                               \
      acc[1][j] = mfma16x32((a1_), b, acc[1][j]);                               \
    }                                                                           \
    __builtin_amdgcn_s_setprio(0);                                              \
  } while(0)

#define MFMA13(a0_, BUF) do {                                                   \
    __builtin_amdgcn_s_setprio(1);                                              \
    _Pragma("unroll")                                                           \
    for (int j=0;j<13;j++){                                                     \
      int tj = ch*13 + j;                                                       \
      f16x8 b = rdB((BUF), tj>>1, tj&1, lhi, l15);                              \
      acc[j] = mfma16x32((a0_), b, acc[j]);                                     \
    }                                                                           \
    __builtin_amdgcn_s_setprio(0);                                              \
  } while(0)

// BK=64 staging over 4 waves: kh-major 26+26 units; half phase = 26 (kh0 only).
#define STAGE_W(wb_, buf_, p_, full_) do{                                       \
    int tot_ = (full_) ? 52 : 26;                                               \
    for (int u = wv; u < tot_; u += 4){                                         \
      int kh_ = (u >= 26) ? 1 : 0, uu_ = u - (kh_ ? 26 : 0);                    \
      stage_duo((wb_), (char*)(buf_)[kh_], 2*(p_)+kh_, 0, uu_>>1, uu_&1, lane); \
    }                                                                           \
  } while(0)

// experts: R15 champion form — BM=64, 4 waves, lact, 2 blocks/CU, VM(0) 2-barrier,
// K-rotation keyed (bx+by)&1. UNCHANGED.
__global__ __launch_bounds__(256,2) void k_experts(
    const f16* __restrict__ h16, const f16* __restrict__ w1T, const float* __restrict__ b1s,
    const f16* __restrict__ w2T, const float* __restrict__ b2s,
    f16* __restrict__ e16, const float* __restrict__ kqg, const int* __restrict__ task,
    float* __restrict__ scores)
{
  __shared__ f16 bufB[13*1024];
  __shared__ f16 lact[64*416];
  float (*psum)[2] = (float(*)[2])lact;
  const int tid = threadIdx.x, lane = tid & 63, wv = tid >> 6;
  const int l15 = lane & 15, lhi = lane >> 4;
  const int rh = wv >> 1, ch = wv & 1;
  const int n = blockIdx.x;
  const int rowbase = blockIdx.y * 64;
  const int K0 = ((blockIdx.x + blockIdx.y) & 1) * 7;
  const f32x4 Z4 = {0,0,0,0};
  f32x4 acc[2][13];

  const char* wb1 = (const char*)(w1T + (size_t)n*DP*DP);
  const char* wb2 = (const char*)(w2T + (size_t)n*DP*DP);
  const f16* Ab = h16 + (size_t)(rowbase + rh*32 + l15)*DP;

  #pragma unroll
  for (int j=0;j<13;j++){ acc[0][j]=Z4; acc[1][j]=Z4; }
  f16x8 a0 = *(const f16x8*)(Ab + K0*32 + lhi*8);
  f16x8 a1 = *(const f16x8*)(Ab + 16*DP + K0*32 + lhi*8);
  stageB4(wb1, (char*)bufB, K0, wv, lane);
  for (int kt=0; kt<NKT; kt++){
    VM(0); BAR();
    MFMA26(a0, a1, bufB);
    BAR();
    if (kt < NKT-1){
      int kn = kt + 1 + K0; if (kn >= NKT) kn -= NKT;
      a0 = *(const f16x8*)(Ab + kn*32 + lhi*8);
      a1 = *(const f16x8*)(Ab + 16*DP + kn*32 + lhi*8);
      stageB4(wb1, (char*)bufB, kn, wv, lane);
    }
  }
  stageB4(wb2, (char*)bufB, K0, wv, lane);
  #pragma unroll
  for (int j=0;j<13;j++){
    int col = (ch*13+j)*16 + l15;
    float bv = (col<D)? b1s[n*D+col] : 0.f;
    #pragma unroll
    for (int ar=0;ar<2;ar++)
      #pragma unroll
      for (int rr=0;rr<4;rr++){
        float v = acc[ar][j][rr] + bv; v = v>0.f?v:0.f;
        lact[lact_idx(rh*32+ar*16+lhi*4+rr, col)] = (f16)v;
      }
  }
  LGKM0;

  #pragma unroll
  for (int j=0;j<13;j++){ acc[0][j]=Z4; acc[1][j]=Z4; }
  for (int kt=0; kt<NKT; kt++){
    int ka = kt + K0; if (ka >= NKT) ka -= NKT;
    VM(0); BAR();
    f16x8 x0 = rdL(lact, rh*32 + l15, ka, lhi);
    f16x8 x1 = rdL(lact, rh*32 + 16 + l15, ka, lhi);
    MFMA26(x0, x1, bufB);
    BAR();
    if (kt < NKT-1){
      int kn = kt + 1 + K0; if (kn >= NKT) kn -= NKT;
      stageB4(wb2, (char*)bufB, kn, wv, lane);
    }
  }
  const float* kqp[2][4];
  const float* kqb = kqg + (size_t)n*NTASK*DP;
  #pragma unroll
  for (int ar=0;ar<2;ar++)
    #pragma unroll
    for (int rr=0;rr<4;rr++){
      int grow = rowbase + rh*32 + ar*16 + lhi*4 + rr;
      kqp[ar][rr] = kqb + (size_t)task[grow]*DP;
    }
  float p_[2][4] = {{0,0,0,0},{0,0,0,0}};
  #pragma unroll
  for (int j=0;j<13;j++){
    int col = (ch*13+j)*16 + l15;
    float bv = (col<D)? b2s[n*D+col] : 0.f;
    #pragma unroll
    for (int ar=0;ar<2;ar++)
      #pragma unroll
      for (int rr=0;rr<4;rr++){
        float v = acc[ar][j][rr] + bv; v = v>0.f?v:0.f;
        e16[((size_t)n*NB + rowbase + rh*32+ar*16+lhi*4+rr)*DP + col] = (f16)v;
        p_[ar][rr] += v * kqp[ar][rr][col];
      }
  }
  #pragma unroll
  for (int ar=0;ar<2;ar++)
    #pragma unroll
    for (int rr=0;rr<4;rr++){
      float p = p_[ar][rr];
      p += __shfl_xor(p, 1, 64);
      p += __shfl_xor(p, 2, 64);
      p += __shfl_xor(p, 4, 64);
      p += __shfl_xor(p, 8, 64);
      if (l15 == 0) psum[rh*32+ar*16+lhi*4+rr][ch] = p;
    }
  LGKM0; BAR();
  if (tid < 64) scores[(size_t)(rowbase + tid)*NEXP + n] = psum[tid][0] + psum[tid][1];
}

// backbone: UNCHANGED champion
__global__ __launch_bounds__(256,2) void k_backbone(
    const f16* __restrict__ x, const f16* __restrict__ w1T, const float* __restrict__ b1,
    const f16* __restrict__ w2T, const float* __restrict__ b2, f16* __restrict__ h16)
{
  __shared__ f16 bufB[2][13*1024];
  __shared__ f16 lact[32*416];
  const int tid = threadIdx.x, lane = tid & 63, wv = tid >> 6;
  const int l15 = lane & 15, lhi = lane >> 4;
  const int rh = wv >> 1, ch = wv & 1;
  const int rowbase = blockIdx.x * 32;
  const int P0 = (blockIdx.x & 1) * 3;
  const f32x4 Z4 = {0,0,0,0};
  f32x4 acc[13];

  const f16* Ab = x + (size_t)(rowbase + rh*16 + l15)*64;

  #pragma unroll
  for (int j=0;j<13;j++) acc[j]=Z4;
  STAGE_W((const char*)w1T, bufB, 0, 1);
  f16x8 a0 = *(const f16x8*)(Ab + lhi*8);
  f16x8 a1 = *(const f16x8*)(Ab + 32 + lhi*8);
  VM(0); BAR();
  MFMA13(a0, bufB[0]);
  MFMA13(a1, bufB[1]);
  BAR();
  { int pa0 = P0; STAGE_W((const char*)w2T, bufB, pa0, pa0 != 6); }
  #pragma unroll
  for (int j=0;j<13;j++){
    int col = (ch*13+j)*16 + l15;
    float bv = (col<D)? b1[col] : 0.f;
    #pragma unroll
    for (int rr=0;rr<4;rr++){
      float v = acc[j][rr] + bv; v = v>0.f?v:0.f;
      lact[lact_idx(rh*16+lhi*4+rr, col)] = (f16)v;
    }
  }
  LGKM0;

  #pragma unroll
  for (int j=0;j<13;j++) acc[j]=Z4;
  for (int p=0; p<7; p++){
    int pa = p + P0; if (pa >= 7) pa -= 7;
    VM(0); BAR();
    f16x8 x0 = rdL(lact, rh*16 + l15, 2*pa, lhi);
    MFMA13(x0, bufB[0]);
    if (pa != 6){
      f16x8 x1 = rdL(lact, rh*16 + l15, 2*pa+1, lhi);
      MFMA13(x1, bufB[1]);
    }
    BAR();
    if (p < 6){
      int pn = p + 1 + P0; if (pn >= 7) pn -= 7;
      STAGE_W((const char*)w2T, bufB, pn, pn != 6);
    }
  }
  #pragma unroll
  for (int j=0;j<13;j++){
    int col = (ch*13+j)*16 + l15;
    float bv = (col<D)? b2[col] : 0.f;
    #pragma unroll
    for (int rr=0;rr<4;rr++){
      float v = acc[j][rr] + bv; v = v>0.f?v:0.f;
      h16[(size_t)(rowbase + rh*16+lhi*4+rr)*DP + col] = (f16)v;
    }
  }
}

// attn: BK=128 — 4 kt sub-buffers per phase, 4 phases/expert, 32 phases total.
// Same sync discipline as champion (VM(0)+BAR top, stage+A-prefetch bottom),
// rotation S0 = parity*16 (multiple of 4 -> p0=0). LDS 57.3KB -> 2 blocks/CU.
__global__ __launch_bounds__(256,2) void k_attn(
    const f16* __restrict__ e16, const f16* __restrict__ valT,
    const float* __restrict__ scores, f16* __restrict__ ti16)
{
  __shared__ f16 buf[4][7*1024];
  __shared__ float wsm[64*NEXP];
  const int tid = threadIdx.x, lane = tid & 63, wv = tid >> 6;
  const int l15 = lane & 15, lhi = lane >> 4;
  const int rg = wv >> 1, cg = wv & 1;
  const int cb = blockIdx.x;
  const int rowbase = blockIdx.y * 64;
  const int nd = cb ? 6 : 7;
  const int ntw = cb ? 6 : 7;
  const int t0 = cb * 14;
  const int S0 = ((blockIdx.x + blockIdx.y) & 1) * 16;   // 32 phases; 16 = half
  const f32x4 Z4 = {0,0,0,0};
  f32x4 acc[2][7];
  #pragma unroll
  for (int a=0;a<2;a++)
    #pragma unroll
    for (int j=0;j<7;j++) acc[a][j]=Z4;

  if (tid < 64){
    const float* sr = scores + (size_t)(rowbase + tid)*NEXP;
    float s[8]; float m = -1e30f;
    #pragma unroll
    for (int k=0;k<8;k++){ s[k]=sr[k]; m = fmaxf(m, s[k]); }
    float sum = 0.f;
    #pragma unroll
    for (int k=0;k<8;k++){ s[k] = expf(s[k]-m); sum += s[k]; }
    float inv = 1.f/sum;
    #pragma unroll
    for (int k=0;k<8;k++) wsm[tid*NEXP + k] = s[k]*inv;
  }

  // stage phase (n,p): sub-buffers q hold kt = 4p+q; p<3 full (q=0..3), p=3: q=0 only
  #define STAGE_A4(n_, p_) do {                                                 \
    const char* vb_ = (const char*)(valT + (size_t)(n_)*DP*DP);                 \
    int nq_ = ((p_) < 3) ? 4 : 1;                                               \
    for (int q_ = 0; q_ < nq_; q_++)                                            \
      for (int u = wv; u < nd*2; u += 4)                                        \
        stage_duo(vb_, (char*)buf[q_], 4*(p_)+q_, t0, u>>1, u&1, lane);         \
  } while(0)

  #define LDA_A(n_, kt_, ar_) \
    (*(const f16x8*)(e16 + ((size_t)(n_)*NB + rowbase + rg*32 + (ar_)*16 + l15)*DP + (kt_)*32 + lhi*8))

  f16x8 aA[4][2];
  const int nS = S0 >> 2;                  // first expert (p0 = 0)
  STAGE_A4(nS, 0);
  #pragma unroll
  for (int q=0;q<4;q++){ aA[q][0] = LDA_A(nS, q, 0); aA[q][1] = LDA_A(nS, q, 1); }
  LGKM0;                                   // wsm drained; loop-top BAR publishes

  for (int s=0;s<32;s++){
    int sa = s + S0; if (sa >= 32) sa -= 32;
    int n = sa >> 2, p = sa & 3;
    VM(0); BAR();
    f16 w0 = (f16)wsm[(rg*32      + l15)*NEXP + n];
    f16 w1 = (f16)wsm[(rg*32 + 16 + l15)*NEXP + n];
    int nq = (p < 3) ? 4 : 1;
    #pragma unroll
    for (int q=0;q<4;q++) if (q < nq){
      f16x8 as0 = scale8(aA[q][0], w0), as1 = scale8(aA[q][1], w1);
      __builtin_amdgcn_s_setprio(1);
      #pragma unroll
      for (int j=0;j<7;j++) if (j<ntw){
        int tl = cg*ntw + j;
        f16x8 b = rdB(buf[q], tl>>1, tl&1, lhi, l15);
        acc[0][j] = mfma16x32(as0, b, acc[0][j]);
        acc[1][j] = mfma16x32(as1, b, acc[1][j]);
      }
      __builtin_amdgcn_s_setprio(0);
    }
    BAR();
    if (s < 31){
      int sa2 = sa + 1; if (sa2 >= 32) sa2 -= 32;
      int n2 = sa2 >> 2, p2 = sa2 & 3;
      STAGE_A4(n2, p2);
      int nq2 = (p2 < 3) ? 4 : 1;
      #pragma unroll
      for (int q=0;q<4;q++) if (q < nq2){
        aA[q][0] = LDA_A(n2, 4*p2+q, 0);
        aA[q][1] = LDA_A(n2, 4*p2+q, 1);
      }
    }
  }
  #pragma unroll
  for (int ar=0;ar<2;ar++)
    #pragma unroll
    for (int j=0;j<7;j++) if (j<ntw){
      int col = (t0 + cg*ntw + j)*16 + l15;
      #pragma unroll
      for (int rr=0;rr<4;rr++)
        ti16[(size_t)(rowbase + rg*32 + ar*16 + lhi*4 + rr)*DP + col] = (f16)acc[ar][j][rr];
    }
}

// mlp3: UNCHANGED champion
__global__ __launch_bounds__(256,2) void k_mlp3(
    const f16* __restrict__ ti16,
    const f16* __restrict__ tw1T, const float* __restrict__ tb1,
    const f16* __restrict__ tw2T, const float* __restrict__ tb2,
    const float* __restrict__ tw3, const float* __restrict__ tb3,
    float* __restrict__ out)
{
  __shared__ f16 bufB[2][13*1024];
  __shared__ f16 lact[32*416];
  float (*psum)[2] = (float(*)[2])lact;
  const int tid = threadIdx.x, lane = tid & 63, wv = tid >> 6;
  const int l15 = lane & 15, lhi = lane >> 4;
  const int rh = wv >> 1, ch = wv & 1;
  const int rowbase = blockIdx.x * 32;
  const int P0 = (blockIdx.x & 1) * 3;
  const f32x4 Z4 = {0,0,0,0};
  f32x4 acc[13];

  const f16* Ab = ti16 + (size_t)(rowbase + rh*16 + l15)*DP;

  #pragma unroll
  for (int j=0;j<13;j++) acc[j]=Z4;
  STAGE_W((const char*)tw1T, bufB, P0, P0 != 6);
  f16x8 a0 = *(const f16x8*)(Ab + (2*P0)*32 + lhi*8);
  f16x8 a1 = (P0 != 6) ? *(const f16x8*)(Ab + (2*P0+1)*32 + lhi*8) : a0;
  for (int p=0; p<7; p++){
    int pa = p + P0; if (pa >= 7) pa -= 7;
    VM(0); BAR();
    MFMA13(a0, bufB[0]);
    if (pa != 6) MFMA13(a1, bufB[1]);
    BAR();
    if (p < 6){
      int pn = p + 1 + P0; if (pn >= 7) pn -= 7;
      STAGE_W((const char*)tw1T, bufB, pn, pn != 6);
      a0 = *(const f16x8*)(Ab + (2*pn)*32 + lhi*8);
      if (pn != 6) a1 = *(const f16x8*)(Ab + (2*pn+1)*32 + lhi*8);
    }
  }
  { int pa0 = P0; STAGE_W((const char*)tw2T, bufB, pa0, pa0 != 6); }
  #pragma unroll
  for (int j=0;j<13;j++){
    int col = (ch*13+j)*16 + l15;
    float bv = (col<D)? tb1[col] : 0.f;
    #pragma unroll
    for (int rr=0;rr<4;rr++){
      float v = acc[j][rr] + bv; v = v>0.f?v:0.f;
      lact[lact_idx(rh*16+lhi*4+rr, col)] = (f16)v;
    }
  }
  LGKM0;

  #pragma unroll
  for (int j=0;j<13;j++) acc[j]=Z4;
  for (int p=0; p<7; p++){
    int pa = p + P0; if (pa >= 7) pa -= 7;
    VM(0); BAR();
    f16x8 x0 = rdL(lact, rh*16 + l15, 2*pa, lhi);
    MFMA13(x0, bufB[0]);
    if (pa != 6){
      f16x8 x1 = rdL(lact, rh*16 + l15, 2*pa+1, lhi);
      MFMA13(x1, bufB[1]);
    }
    BAR();
    if (p < 6){
      int pn = p + 1 + P0; if (pn >= 7) pn -= 7;
      STAGE_W((const char*)tw2T, bufB, pn, pn != 6);
    }
  }
  float p_[4] = {0,0,0,0};
  #pragma unroll
  for (int j=0;j<13;j++){
    int col = (ch*13+j)*16 + l15;
    float bv = (col<D)? tb2[col] : 0.f;
    float w3 = (col<D)? tw3[col] : 0.f;
    #pragma unroll
    for (int rr=0;rr<4;rr++){
      float v = acc[j][rr] + bv; v = v>0.f?v:0.f;
      p_[rr] += v * w3;
    }
  }
  #pragma unroll
  for (int rr=0;rr<4;rr++){
    float p = p_[rr];
    p += __shfl_xor(p, 1, 64);
    p += __shfl_xor(p, 2, 64);
    p += __shfl_xor(p, 4, 64);
    p += __shfl_xor(p, 8, 64);
    if (l15 == 0) psum[rh*16+lhi*4+rr][ch] = p;
  }
  LGKM0; BAR();
  if (tid < 32) out[rowbase + tid] = psum[tid][0] + psum[tid][1] + tb3[0];
}

// ---------------- launcher ----------------

extern "C" void kernel_launch(void* const* d_in, const int* in_sizes, int n_in,
                              void* d_out, int out_size, void* d_ws, size_t ws_size,
                              hipStream_t stream)
{
  const float* obs     = (const float*)d_in[0];
  const float* act     = (const float*)d_in[1];
  const int*   task    = (const int*)  d_in[2];
  const float* bb_w1   = (const float*)d_in[3];
  const float* bb_b1   = (const float*)d_in[4];
  const float* bb_w2   = (const float*)d_in[5];
  const float* bb_b2   = (const float*)d_in[6];
  const float* ex_w1   = (const float*)d_in[7];
  const float* ex_b1   = (const float*)d_in[8];
  const float* ex_w2   = (const float*)d_in[9];
  const float* ex_b2   = (const float*)d_in[10];
  const float* key_mat = (const float*)d_in[11];
  const float* val_mat = (const float*)d_in[12];
  const float* tq      = (const float*)d_in[13];
  const float* tw_w1   = (const float*)d_in[14];
  const float* tw_b1   = (const float*)d_in[15];
  const float* tw_w2   = (const float*)d_in[16];
  const float* tw_b2   = (const float*)d_in[17];
  const float* tw_w3   = (const float*)d_in[18];
  const float* tw_b3   = (const float*)d_in[19];

  char* ws = (char*)d_ws;
  size_t off = 0;
  auto alloc = [&](size_t bytes){ void* p = ws + off; off += (bytes + 255) & ~(size_t)255; return p; };
  f16*   x16   = (f16*)  alloc((size_t)NB*64*2);
  f16*   h16   = (f16*)  alloc((size_t)NB*DP*2);
  f16*   e16   = (f16*)  alloc((size_t)NEXP*NB*DP*2);
  f16*   ti16  = (f16*)  alloc((size_t)NB*DP*2);
  float* scors = (float*)alloc((size_t)NB*NEXP*4);
  float* kq    = (float*)alloc((size_t)NEXP*NTASK*DP*4);
  f16*   bbw1T = (f16*)  alloc((size_t)DP*DP*2);
  f16*   bbw2T = (f16*)  alloc((size_t)DP*DP*2);
  f16*   exw1T = (f16*)  alloc((size_t)NEXP*DP*DP*2);
  f16*   exw2T = (f16*)  alloc((size_t)NEXP*DP*DP*2);
  f16*   valT  = (f16*)  alloc((size_t)NEXP*DP*DP*2);
  f16*   tw1T  = (f16*)  alloc((size_t)DP*DP*2);
  f16*   tw2T  = (f16*)  alloc((size_t)DP*DP*2);
  (void)ws_size; (void)in_sizes; (void)n_in; (void)out_size;

  k_build_x<<<NB*64/256, 256, 0, stream>>>(obs, act, x16);
  k_transpose_all<<<dim3(13,13,20), 256, 0, stream>>>(
      bb_w1, bb_w2, ex_w1, ex_w2, tw_w1, tw_w2,
      bbw1T, bbw2T, exw1T, exw2T, tw1T, tw2T);
  k_val_pad<<<(NEXP*DP*DP + 255)/256, 256, 0, stream>>>(val_mat, valT);
  k_kq<<<dim3(NEXP, 13), 256, 0, stream>>>(key_mat, tq, kq);

  k_backbone<<<NB/32, 256, 0, stream>>>(x16, bbw1T, bb_b1, bbw2T, bb_b2, h16);
  k_experts<<<dim3(NEXP, NB/64), 256, 0, stream>>>(h16, exw1T, ex_b1, exw2T, ex_b2,
                                                   e16, kq, task, scors);
  k_attn<<<dim3(2, NB/64), 256, 0, stream>>>(e16, valT, scors, ti16);
  k_mlp3<<<NB/32, 256, 0, stream>>>(ti16, tw1T, tw_b1, tw2T, tw_b2, tw_w3, tw_b3,
                                    (float*)d_out);
}

// Round 19
// 334.043 us; speedup vs baseline: 1.2930x; 1.0349x over previous
//
#include <hip/hip_runtime.h>

typedef _Float16 f16;
typedef f16 f16x8 __attribute__((ext_vector_type(8)));
typedef float f32x4 __attribute__((ext_vector_type(4)));

#define NB 16384
#define D 400
#define DP 416
#define NEXP 8
#define NTASK 10
#define NKT 13

#define MEMFENCE asm volatile("" ::: "memory")
#define BAR() do{ MEMFENCE; __builtin_amdgcn_s_barrier(); MEMFENCE; }while(0)
#define VM(N) asm volatile("s_waitcnt vmcnt(" #N ")" ::: "memory")
#define LGKM0 asm volatile("s_waitcnt lgkmcnt(0)" ::: "memory")

static __device__ __forceinline__ f32x4 mfma16x32(f16x8 a, f16x8 b, f32x4 c){
  return __builtin_amdgcn_mfma_f32_16x16x32_f16(a, b, c, 0, 0, 0);
}
static __device__ __forceinline__ void g2l(const void* g, void* l){
  __builtin_amdgcn_global_load_lds((const __attribute__((address_space(1))) void*)g,
      (__attribute__((address_space(3))) void*)l, 16, 0, 0);
}
static __device__ __forceinline__ f16x8 scale8(f16x8 a, f16 s){
  f16x8 r;
  #pragma unroll
  for (int e=0;e<8;e++) r[e] = a[e]*s;
  return r;
}

// ---- duo staging (verified R4/R6/R9/R10): 2 adjacent 16-col tiles for one kt,
// [16 rows][128B], chunk ^= row&7; LDS dest linear, global source pre-swizzled.
static __device__ __forceinline__ void stage_duo(const char* wbase, char* lds, int kt,
                                                 int t0, int dd, int h, int lane){
  const int r = lane >> 3, c = lane & 7, cg = c ^ r;
  g2l(wbase + (size_t)((t0 + dd*2 + (cg>>2))*16 + h*8 + r)*832 + (size_t)kt*64 + (cg&3)*16,
      lds + dd*2048 + h*1024);
}
static __device__ __forceinline__ f16x8 rdB(const f16* buf, int dloc, int t, int lhi, int l15){
  return *(const f16x8*)(buf + dloc*1024 + l15*64 + ((((t*4+lhi) ^ (l15&7)))<<3));
}
// lact: [rows][416] f16, 16B-chunk XOR swizzle on chunks<48
static __device__ __forceinline__ f16x8 rdL(const f16* lact, int r, int kt, int lhi){
  int q = kt*4 + lhi;
  int c = (q < 48) ? (q ^ (r&7)) : q;
  return *(const f16x8*)(lact + r*416 + (c<<3));
}
static __device__ __forceinline__ int lact_idx(int r, int col){
  int q = col >> 3;
  int c = (q < 48) ? (q ^ (r&7)) : q;
  return r*416 + (c<<3) + (col&7);
}
// full-width 416-col staging for one kt: 26 units of 1KB over 4 waves
static __device__ __forceinline__ void stageB4(const char* wb, char* buf, int kt,
                                               int wv, int lane){
  for (int u = wv; u < 26; u += 4) stage_duo(wb, buf, kt, 0, u>>1, u&1, lane);
}

// ---------------- prep kernels ----------------

__global__ void k_build_x(const float* __restrict__ obs, const float* __restrict__ act,
                          f16* __restrict__ x)
{
  int idx = blockIdx.x*256 + threadIdx.x;
  int b = idx >> 6, c = idx & 63;
  float v = 0.f;
  if (c < 39) v = obs[b*39 + c];
  else if (c < 43) v = act[b*4 + (c - 39)];
  x[idx] = (f16)v;
}

__global__ void k_transpose_all(
    const float* __restrict__ bb_w1, const float* __restrict__ bb_w2,
    const float* __restrict__ ex_w1, const float* __restrict__ ex_w2,
    const float* __restrict__ tw_w1, const float* __restrict__ tw_w2,
    f16* __restrict__ bbw1T, f16* __restrict__ bbw2T,
    f16* __restrict__ exw1T, f16* __restrict__ exw2T,
    f16* __restrict__ tw1T,  f16* __restrict__ tw2T)
{
  __shared__ float t[32][33];
  const int z = blockIdx.z;
  const float* in; f16* out; int K = D;
  if (z == 0){ in = bb_w1; out = bbw1T; K = 43; }
  else if (z == 1){ in = bb_w2; out = bbw2T; }
  else if (z < 10){ in = ex_w1 + (size_t)(z-2)*D*D;  out = exw1T + (size_t)(z-2)*DP*DP; }
  else if (z < 18){ in = ex_w2 + (size_t)(z-10)*D*D; out = exw2T + (size_t)(z-10)*DP*DP; }
  else if (z == 18){ in = tw_w1; out = tw1T; }
  else { in = tw_w2; out = tw2T; }
  int tx = threadIdx.x & 31, ty = threadIdx.x >> 5;
  int n0 = blockIdx.x*32, k0 = blockIdx.y*32;
  #pragma unroll
  for (int r=0;r<4;r++){
    int k = k0 + ty + r*8, nn = n0 + tx;
    t[ty + r*8][tx] = (k < K && nn < D) ? in[(size_t)k*D + nn] : 0.f;
  }
  __syncthreads();
  #pragma unroll
  for (int r=0;r<4;r++){
    int nn = n0 + ty + r*8, kp = k0 + tx;
    if (nn < DP && kp < DP) out[(size_t)nn*DP + kp] = (f16)t[tx][ty + r*8];
  }
}

__global__ void k_val_pad(const float* __restrict__ in, f16* __restrict__ out)
{
  int idx = blockIdx.x*256 + threadIdx.x;
  if (idx >= NEXP*DP*DP) return;
  int c = idx % DP, r = (idx / DP) % DP, n = idx / (DP*DP);
  float v = (r < D && c < D) ? in[((size_t)n*D + r)*D + c] : 0.f;
  out[idx] = (f16)v;
}

// kq: col-split grid (NEXP, 13); km column panel staged in LDS. (verified R12)
__global__ void k_kq(const float* __restrict__ key_mat, const float* __restrict__ tq,
                     float* __restrict__ kq)
{
  __shared__ float kcol[D*32];
  __shared__ float tqs[NTASK*D];
  const int n = blockIdx.x, cb = blockIdx.y, tid = threadIdx.x;
  const int c0 = cb*32;
  const float* km = key_mat + (size_t)n*D*D;
  for (int idx=tid; idx<NTASK*D; idx+=256) tqs[idx] = tq[idx];
  for (int idx=tid; idx<D*32; idx+=256){
    int i = idx>>5, c = idx&31;
    int col = c0 + c;
    kcol[idx] = (col < D) ? km[(size_t)i*D + col] : 0.f;
  }
  __syncthreads();
  const int c = tid & 31, tg = tid >> 5;
  #pragma unroll
  for (int rep=0; rep<2; rep++){
    int t = tg + rep*8;
    if (t < NTASK){
      float acc = 0.f;
      for (int i=0;i<D;i++) acc += kcol[i*32+c] * tqs[t*D+i];
      int col = c0 + c;
      if (col < DP) kq[((size_t)n*NTASK + t)*DP + col] = acc;
    }
  }
}

// ---------------- compute kernels ----------------

#define MFMA26(a0_, a1_, BUF) do {                                              \
    __builtin_amdgcn_s_setprio(1);                                              \
    _Pragma("unroll")                                                           \
    for (int j=0;j<13;j++){                                                     \
      int tj = ch*13 + j;                                                       \
      f16x8 b = rdB((BUF), tj>>1, tj&1, lhi, l15);                              \
      acc[0][j] = mfma16x32((a0_), b, acc[0][j]);                               \
      acc[1][j] = mfma16x32((a1_), b, acc[1][j]);                               \
    }                                                                           \
    __builtin_amdgcn_s_setprio(0);                                              \
  } while(0)

#define MFMA13(a0_, BUF) do {                                                   \
    __builtin_amdgcn_s_setprio(1);                                              \
    _Pragma("unroll")                                                           \
    for (int j=0;j<13;j++){                                                     \
      int tj = ch*13 + j;                                                       \
      f16x8 b = rdB((BUF), tj>>1, tj&1, lhi, l15);                              \
      acc[j] = mfma16x32((a0_), b, acc[j]);                                     \
    }                                                                           \
    __builtin_amdgcn_s_setprio(0);                                              \
  } while(0)

// BK=64 staging over 4 waves: kh-major 26+26 units; half phase = 26 (kh0 only).
#define STAGE_W(wb_, buf_, p_, full_) do{                                       \
    int tot_ = (full_) ? 52 : 26;                                               \
    for (int u = wv; u < tot_; u += 4){                                         \
      int kh_ = (u >= 26) ? 1 : 0, uu_ = u - (kh_ ? 26 : 0);                    \
      stage_duo((wb_), (char*)(buf_)[kh_], 2*(p_)+kh_, 0, uu_>>1, uu_&1, lane); \
    }                                                                           \
  } while(0)

// experts: R15 champion form — UNCHANGED.
__global__ __launch_bounds__(256,2) void k_experts(
    const f16* __restrict__ h16, const f16* __restrict__ w1T, const float* __restrict__ b1s,
    const f16* __restrict__ w2T, const float* __restrict__ b2s,
    f16* __restrict__ e16, const float* __restrict__ kqg, const int* __restrict__ task,
    float* __restrict__ scores)
{
  __shared__ f16 bufB[13*1024];
  __shared__ f16 lact[64*416];
  float (*psum)[2] = (float(*)[2])lact;
  const int tid = threadIdx.x, lane = tid & 63, wv = tid >> 6;
  const int l15 = lane & 15, lhi = lane >> 4;
  const int rh = wv >> 1, ch = wv & 1;
  const int n = blockIdx.x;
  const int rowbase = blockIdx.y * 64;
  const int K0 = ((blockIdx.x + blockIdx.y) & 1) * 7;
  const f32x4 Z4 = {0,0,0,0};
  f32x4 acc[2][13];

  const char* wb1 = (const char*)(w1T + (size_t)n*DP*DP);
  const char* wb2 = (const char*)(w2T + (size_t)n*DP*DP);
  const f16* Ab = h16 + (size_t)(rowbase + rh*32 + l15)*DP;

  #pragma unroll
  for (int j=0;j<13;j++){ acc[0][j]=Z4; acc[1][j]=Z4; }
  f16x8 a0 = *(const f16x8*)(Ab + K0*32 + lhi*8);
  f16x8 a1 = *(const f16x8*)(Ab + 16*DP + K0*32 + lhi*8);
  stageB4(wb1, (char*)bufB, K0, wv, lane);
  for (int kt=0; kt<NKT; kt++){
    VM(0); BAR();
    MFMA26(a0, a1, bufB);
    BAR();
    if (kt < NKT-1){
      int kn = kt + 1 + K0; if (kn >= NKT) kn -= NKT;
      a0 = *(const f16x8*)(Ab + kn*32 + lhi*8);
      a1 = *(const f16x8*)(Ab + 16*DP + kn*32 + lhi*8);
      stageB4(wb1, (char*)bufB, kn, wv, lane);
    }
  }
  stageB4(wb2, (char*)bufB, K0, wv, lane);
  #pragma unroll
  for (int j=0;j<13;j++){
    int col = (ch*13+j)*16 + l15;
    float bv = (col<D)? b1s[n*D+col] : 0.f;
    #pragma unroll
    for (int ar=0;ar<2;ar++)
      #pragma unroll
      for (int rr=0;rr<4;rr++){
        float v = acc[ar][j][rr] + bv; v = v>0.f?v:0.f;
        lact[lact_idx(rh*32+ar*16+lhi*4+rr, col)] = (f16)v;
      }
  }
  LGKM0;

  #pragma unroll
  for (int j=0;j<13;j++){ acc[0][j]=Z4; acc[1][j]=Z4; }
  for (int kt=0; kt<NKT; kt++){
    int ka = kt + K0; if (ka >= NKT) ka -= NKT;
    VM(0); BAR();
    f16x8 x0 = rdL(lact, rh*32 + l15, ka, lhi);
    f16x8 x1 = rdL(lact, rh*32 + 16 + l15, ka, lhi);
    MFMA26(x0, x1, bufB);
    BAR();
    if (kt < NKT-1){
      int kn = kt + 1 + K0; if (kn >= NKT) kn -= NKT;
      stageB4(wb2, (char*)bufB, kn, wv, lane);
    }
  }
  const float* kqp[2][4];
  const float* kqb = kqg + (size_t)n*NTASK*DP;
  #pragma unroll
  for (int ar=0;ar<2;ar++)
    #pragma unroll
    for (int rr=0;rr<4;rr++){
      int grow = rowbase + rh*32 + ar*16 + lhi*4 + rr;
      kqp[ar][rr] = kqb + (size_t)task[grow]*DP;
    }
  float p_[2][4] = {{0,0,0,0},{0,0,0,0}};
  #pragma unroll
  for (int j=0;j<13;j++){
    int col = (ch*13+j)*16 + l15;
    float bv = (col<D)? b2s[n*D+col] : 0.f;
    #pragma unroll
    for (int ar=0;ar<2;ar++)
      #pragma unroll
      for (int rr=0;rr<4;rr++){
        float v = acc[ar][j][rr] + bv; v = v>0.f?v:0.f;
        e16[((size_t)n*NB + rowbase + rh*32+ar*16+lhi*4+rr)*DP + col] = (f16)v;
        p_[ar][rr] += v * kqp[ar][rr][col];
      }
  }
  #pragma unroll
  for (int ar=0;ar<2;ar++)
    #pragma unroll
    for (int rr=0;rr<4;rr++){
      float p = p_[ar][rr];
      p += __shfl_xor(p, 1, 64);
      p += __shfl_xor(p, 2, 64);
      p += __shfl_xor(p, 4, 64);
      p += __shfl_xor(p, 8, 64);
      if (l15 == 0) psum[rh*32+ar*16+lhi*4+rr][ch] = p;
    }
  LGKM0; BAR();
  if (tid < 64) scores[(size_t)(rowbase + tid)*NEXP + n] = psum[tid][0] + psum[tid][1];
}

// backbone: UNCHANGED champion
__global__ __launch_bounds__(256,2) void k_backbone(
    const f16* __restrict__ x, const f16* __restrict__ w1T, const float* __restrict__ b1,
    const f16* __restrict__ w2T, const float* __restrict__ b2, f16* __restrict__ h16)
{
  __shared__ f16 bufB[2][13*1024];
  __shared__ f16 lact[32*416];
  const int tid = threadIdx.x, lane = tid & 63, wv = tid >> 6;
  const int l15 = lane & 15, lhi = lane >> 4;
  const int rh = wv >> 1, ch = wv & 1;
  const int rowbase = blockIdx.x * 32;
  const int P0 = (blockIdx.x & 1) * 3;
  const f32x4 Z4 = {0,0,0,0};
  f32x4 acc[13];

  const f16* Ab = x + (size_t)(rowbase + rh*16 + l15)*64;

  #pragma unroll
  for (int j=0;j<13;j++) acc[j]=Z4;
  STAGE_W((const char*)w1T, bufB, 0, 1);
  f16x8 a0 = *(const f16x8*)(Ab + lhi*8);
  f16x8 a1 = *(const f16x8*)(Ab + 32 + lhi*8);
  VM(0); BAR();
  MFMA13(a0, bufB[0]);
  MFMA13(a1, bufB[1]);
  BAR();
  { int pa0 = P0; STAGE_W((const char*)w2T, bufB, pa0, pa0 != 6); }
  #pragma unroll
  for (int j=0;j<13;j++){
    int col = (ch*13+j)*16 + l15;
    float bv = (col<D)? b1[col] : 0.f;
    #pragma unroll
    for (int rr=0;rr<4;rr++){
      float v = acc[j][rr] + bv; v = v>0.f?v:0.f;
      lact[lact_idx(rh*16+lhi*4+rr, col)] = (f16)v;
    }
  }
  LGKM0;

  #pragma unroll
  for (int j=0;j<13;j++) acc[j]=Z4;
  for (int p=0; p<7; p++){
    int pa = p + P0; if (pa >= 7) pa -= 7;
    VM(0); BAR();
    f16x8 x0 = rdL(lact, rh*16 + l15, 2*pa, lhi);
    MFMA13(x0, bufB[0]);
    if (pa != 6){
      f16x8 x1 = rdL(lact, rh*16 + l15, 2*pa+1, lhi);
      MFMA13(x1, bufB[1]);
    }
    BAR();
    if (p < 6){
      int pn = p + 1 + P0; if (pn >= 7) pn -= 7;
      STAGE_W((const char*)w2T, bufB, pn, pn != 6);
    }
  }
  #pragma unroll
  for (int j=0;j<13;j++){
    int col = (ch*13+j)*16 + l15;
    float bv = (col<D)? b2[col] : 0.f;
    #pragma unroll
    for (int rr=0;rr<4;rr++){
      float v = acc[j][rr] + bv; v = v>0.f?v:0.f;
      h16[(size_t)(rowbase + rh*16+lhi*4+rr)*DP + col] = (f16)v;
    }
  }
}

// attn: BK-grouped phases {4,4,5} — 3 phases/expert, 24 total (48 slots/CU).
// 5 kt sub-buffers (71.7KB LDS -> still 2 blocks/CU). Same sync discipline.
__global__ __launch_bounds__(256,2) void k_attn(
    const f16* __restrict__ e16, const f16* __restrict__ valT,
    const float* __restrict__ scores, f16* __restrict__ ti16)
{
  __shared__ f16 buf[5][7*1024];
  __shared__ float wsm[64*NEXP];
  const int tid = threadIdx.x, lane = tid & 63, wv = tid >> 6;
  const int l15 = lane & 15, lhi = lane >> 4;
  const int rg = wv >> 1, cg = wv & 1;
  const int cb = blockIdx.x;
  const int rowbase = blockIdx.y * 64;
  const int nd = cb ? 6 : 7;
  const int ntw = cb ? 6 : 7;
  const int t0 = cb * 14;
  const int S0 = ((blockIdx.x + blockIdx.y) & 1) * 12;   // 24 phases; 12 = half (12%3==0)
  const f32x4 Z4 = {0,0,0,0};
  f32x4 acc[2][7];
  #pragma unroll
  for (int a=0;a<2;a++)
    #pragma unroll
    for (int j=0;j<7;j++) acc[a][j]=Z4;

  if (tid < 64){
    const float* sr = scores + (size_t)(rowbase + tid)*NEXP;
    float s[8]; float m = -1e30f;
    #pragma unroll
    for (int k=0;k<8;k++){ s[k]=sr[k]; m = fmaxf(m, s[k]); }
    float sum = 0.f;
    #pragma unroll
    for (int k=0;k<8;k++){ s[k] = expf(s[k]-m); sum += s[k]; }
    float inv = 1.f/sum;
    #pragma unroll
    for (int k=0;k<8;k++) wsm[tid*NEXP + k] = s[k]*inv;
  }

  // phase p: kt base KB(p) = {0,4,8}[p], count NQ(p) = {4,4,5}[p]
  #define KB_(p_) ((p_)*4)
  #define NQ_(p_) (((p_)==2)?5:4)
  #define STAGE_A5(n_, p_) do {                                                 \
    const char* vb_ = (const char*)(valT + (size_t)(n_)*DP*DP);                 \
    int nq_ = NQ_(p_), kb_ = KB_(p_);                                           \
    for (int q_ = 0; q_ < nq_; q_++)                                            \
      for (int u = wv; u < nd*2; u += 4)                                        \
        stage_duo(vb_, (char*)buf[q_], kb_+q_, t0, u>>1, u&1, lane);            \
  } while(0)

  #define LDA_A(n_, kt_, ar_) \
    (*(const f16x8*)(e16 + ((size_t)(n_)*NB + rowbase + rg*32 + (ar_)*16 + l15)*DP + (kt_)*32 + lhi*8))

  f16x8 aA[5][2];
  const int nS = S0 / 3;                   // first expert (p0 = 0)
  STAGE_A5(nS, 0);
  #pragma unroll
  for (int q=0;q<4;q++){ aA[q][0] = LDA_A(nS, q, 0); aA[q][1] = LDA_A(nS, q, 1); }
  LGKM0;                                   // wsm drained; loop-top BAR publishes

  for (int s=0;s<24;s++){
    int sa = s + S0; if (sa >= 24) sa -= 24;
    int n = sa / 3, p = sa - n*3;
    VM(0); BAR();
    f16 w0 = (f16)wsm[(rg*32      + l15)*NEXP + n];
    f16 w1 = (f16)wsm[(rg*32 + 16 + l15)*NEXP + n];
    int nq = NQ_(p);
    #pragma unroll
    for (int q=0;q<5;q++) if (q < nq){
      f16x8 as0 = scale8(aA[q][0], w0), as1 = scale8(aA[q][1], w1);
      __builtin_amdgcn_s_setprio(1);
      #pragma unroll
      for (int j=0;j<7;j++) if (j<ntw){
        int tl = cg*ntw + j;
        f16x8 b = rdB(buf[q], tl>>1, tl&1, lhi, l15);
        acc[0][j] = mfma16x32(as0, b, acc[0][j]);
        acc[1][j] = mfma16x32(as1, b, acc[1][j]);
      }
      __builtin_amdgcn_s_setprio(0);
    }
    BAR();
    if (s < 23){
      int sa2 = sa + 1; if (sa2 >= 24) sa2 -= 24;
      int n2 = sa2 / 3, p2 = sa2 - n2*3;
      STAGE_A5(n2, p2);
      int nq2 = NQ_(p2), kb2 = KB_(p2);
      #pragma unroll
      for (int q=0;q<5;q++) if (q < nq2){
        aA[q][0] = LDA_A(n2, kb2+q, 0);
        aA[q][1] = LDA_A(n2, kb2+q, 1);
      }
    }
  }
  #pragma unroll
  for (int ar=0;ar<2;ar++)
    #pragma unroll
    for (int j=0;j<7;j++) if (j<ntw){
      int col = (t0 + cg*ntw + j)*16 + l15;
      #pragma unroll
      for (int rr=0;rr<4;rr++)
        ti16[(size_t)(rowbase + rg*32 + ar*16 + lhi*4 + rr)*DP + col] = (f16)acc[ar][j][rr];
    }
}

// mlp3: UNCHANGED champion
__global__ __launch_bounds__(256,2) void k_mlp3(
    const f16* __restrict__ ti16,
    const f16* __restrict__ tw1T, const float* __restrict__ tb1,
    const f16* __restrict__ tw2T, const float* __restrict__ tb2,
    const float* __restrict__ tw3, const float* __restrict__ tb3,
    float* __restrict__ out)
{
  __shared__ f16 bufB[2][13*1024];
  __shared__ f16 lact[32*416];
  float (*psum)[2] = (float(*)[2])lact;
  const int tid = threadIdx.x, lane = tid & 63, wv = tid >> 6;
  const int l15 = lane & 15, lhi = lane >> 4;
  const int rh = wv >> 1, ch = wv & 1;
  const int rowbase = blockIdx.x * 32;
  const int P0 = (blockIdx.x & 1) * 3;
  const f32x4 Z4 = {0,0,0,0};
  f32x4 acc[13];

  const f16* Ab = ti16 + (size_t)(rowbase + rh*16 + l15)*DP;

  #pragma unroll
  for (int j=0;j<13;j++) acc[j]=Z4;
  STAGE_W((const char*)tw1T, bufB, P0, P0 != 6);
  f16x8 a0 = *(const f16x8*)(Ab + (2*P0)*32 + lhi*8);
  f16x8 a1 = (P0 != 6) ? *(const f16x8*)(Ab + (2*P0+1)*32 + lhi*8) : a0;
  for (int p=0; p<7; p++){
    int pa = p + P0; if (pa >= 7) pa -= 7;
    VM(0); BAR();
    MFMA13(a0, bufB[0]);
    if (pa != 6) MFMA13(a1, bufB[1]);
    BAR();
    if (p < 6){
      int pn = p + 1 + P0; if (pn >= 7) pn -= 7;
      STAGE_W((const char*)tw1T, bufB, pn, pn != 6);
      a0 = *(const f16x8*)(Ab + (2*pn)*32 + lhi*8);
      if (pn != 6) a1 = *(const f16x8*)(Ab + (2*pn+1)*32 + lhi*8);
    }
  }
  { int pa0 = P0; STAGE_W((const char*)tw2T, bufB, pa0, pa0 != 6); }
  #pragma unroll
  for (int j=0;j<13;j++){
    int col = (ch*13+j)*16 + l15;
    float bv = (col<D)? tb1[col] : 0.f;
    #pragma unroll
    for (int rr=0;rr<4;rr++){
      float v = acc[j][rr] + bv; v = v>0.f?v:0.f;
      lact[lact_idx(rh*16+lhi*4+rr, col)] = (f16)v;
    }
  }
  LGKM0;

  #pragma unroll
  for (int j=0;j<13;j++) acc[j]=Z4;
  for (int p=0; p<7; p++){
    int pa = p + P0; if (pa >= 7) pa -= 7;
    VM(0); BAR();
    f16x8 x0 = rdL(lact, rh*16 + l15, 2*pa, lhi);
    MFMA13(x0, bufB[0]);
    if (pa != 6){
      f16x8 x1 = rdL(lact, rh*16 + l15, 2*pa+1, lhi);
      MFMA13(x1, bufB[1]);
    }
    BAR();
    if (p < 6){
      int pn = p + 1 + P0; if (pn >= 7) pn -= 7;
      STAGE_W((const char*)tw2T, bufB, pn, pn != 6);
    }
  }
  float p_[4] = {0,0,0,0};
  #pragma unroll
  for (int j=0;j<13;j++){
    int col = (ch*13+j)*16 + l15;
    float bv = (col<D)? tb2[col] : 0.f;
    float w3 = (col<D)? tw3[col] : 0.f;
    #pragma unroll
    for (int rr=0;rr<4;rr++){
      float v = acc[j][rr] + bv; v = v>0.f?v:0.f;
      p_[rr] += v * w3;
    }
  }
  #pragma unroll
  for (int rr=0;rr<4;rr++){
    float p = p_[rr];
    p += __shfl_xor(p, 1, 64);
    p += __shfl_xor(p, 2, 64);
    p += __shfl_xor(p, 4, 64);
    p += __shfl_xor(p, 8, 64);
    if (l15 == 0) psum[rh*16+lhi*4+rr][ch] = p;
  }
  LGKM0; BAR();
  if (tid < 32) out[rowbase + tid] = psum[tid][0] + psum[tid][1] + tb3[0];
}

// ---------------- launcher ----------------

extern "C" void kernel_launch(void* const* d_in, const int* in_sizes, int n_in,
                              void* d_out, int out_size, void* d_ws, size_t ws_size,
                              hipStream_t stream)
{
  const float* obs     = (const float*)d_in[0];
  const float* act     = (const float*)d_in[1];
  const int*   task    = (const int*)  d_in[2];
  const float* bb_w1   = (const float*)d_in[3];
  const float* bb_b1   = (const float*)d_in[4];
  const float* bb_w2   = (const float*)d_in[5];
  const float* bb_b2   = (const float*)d_in[6];
  const float* ex_w1   = (const float*)d_in[7];
  const float* ex_b1   = (const float*)d_in[8];
  const float* ex_w2   = (const float*)d_in[9];
  const float* ex_b2   = (const float*)d_in[10];
  const float* key_mat = (const float*)d_in[11];
  const float* val_mat = (const float*)d_in[12];
  const float* tq      = (const float*)d_in[13];
  const float* tw_w1   = (const float*)d_in[14];
  const float* tw_b1   = (const float*)d_in[15];
  const float* tw_w2   = (const float*)d_in[16];
  const float* tw_b2   = (const float*)d_in[17];
  const float* tw_w3   = (const float*)d_in[18];
  const float* tw_b3   = (const float*)d_in[19];

  char* ws = (char*)d_ws;
  size_t off = 0;
  auto alloc = [&](size_t bytes){ void* p = ws + off; off += (bytes + 255) & ~(size_t)255; return p; };
  f16*   x16   = (f16*)  alloc((size_t)NB*64*2);
  f16*   h16   = (f16*)  alloc((size_t)NB*DP*2);
  f16*   e16   = (f16*)  alloc((size_t)NEXP*NB*DP*2);
  f16*   ti16  = (f16*)  alloc((size_t)NB*DP*2);
  float* scors = (float*)alloc((size_t)NB*NEXP*4);
  float* kq    = (float*)alloc((size_t)NEXP*NTASK*DP*4);
  f16*   bbw1T = (f16*)  alloc((size_t)DP*DP*2);
  f16*   bbw2T = (f16*)  alloc((size_t)DP*DP*2);
  f16*   exw1T = (f16*)  alloc((size_t)NEXP*DP*DP*2);
  f16*   exw2T = (f16*)  alloc((size_t)NEXP*DP*DP*2);
  f16*   valT  = (f16*)  alloc((size_t)NEXP*DP*DP*2);
  f16*   tw1T  = (f16*)  alloc((size_t)DP*DP*2);
  f16*   tw2T  = (f16*)  alloc((size_t)DP*DP*2);
  (void)ws_size; (void)in_sizes; (void)n_in; (void)out_size;

  k_build_x<<<NB*64/256, 256, 0, stream>>>(obs, act, x16);
  k_transpose_all<<<dim3(13,13,20), 256, 0, stream>>>(
      bb_w1, bb_w2, ex_w1, ex_w2, tw_w1, tw_w2,
      bbw1T, bbw2T, exw1T, exw2T, tw1T, tw2T);
  k_val_pad<<<(NEXP*DP*DP + 255)/256, 256, 0, stream>>>(val_mat, valT);
  k_kq<<<dim3(NEXP, 13), 256, 0, stream>>>(key_mat, tq, kq);

  k_backbone<<<NB/32, 256, 0, stream>>>(x16, bbw1T, bb_b1, bbw2T, bb_b2, h16);
  k_experts<<<dim3(NEXP, NB/64), 256, 0, stream>>>(h16, exw1T, ex_b1, exw2T, ex_b2,
                                                   e16, kq, task, scors);
  k_attn<<<dim3(2, NB/64), 256, 0, stream>>>(e16, valT, scors, ti16);
  k_mlp3<<<NB/32, 256, 0, stream>>>(ti16, tw1T, tw_b1, tw2T, tw_b2, tw_w3, tw_b3,
                                    (float*)d_out);
}